// Round 5
// baseline (308.087 us; speedup 1.0000x reference)
//
#include <hip/hip_runtime.h>
#include <hip/hip_fp16.h>

// GraphEmbedNet: 3-layer GCN, N=50000, E=800000, F=128/128/64.
// R18 (R17 post-mortem): agg_kernel showed VGPR_Count=32 -- the compiler
// register-squeezed the 16-deep gather batch (needs ~90 live VGPRs) into the
// 8-waves/SIMD occupancy bucket and SERIALIZED the e->f load chains. Same
// failure mode as R14's 28-VGPR fused kernel. Fix: __launch_bounds__(256, 4)
// caps at 128 VGPR (4 waves/SIMD, 16 waves/CU -- still enough TLP) so the
// 16-deep pipeline stays in registers. p2_sort reverted to R16/R13-exact
// 256-thread form (R17's quarter-private variant is confounded in the +13us
// regression; re-test separately if ever).
// Everything else R16-identical.

#define K_DIM 128
#define SORT_ITEMS 4096   // elements per pass-1 block

typedef unsigned long long u64;
typedef unsigned int u32;

using half8   = __attribute__((ext_vector_type(8))) _Float16;
using floatx4 = __attribute__((ext_vector_type(4))) float;

// ---------------- sort-based CSR build ----------------

// fused: pack edges + self-loops AND per-block 256-bin hist of high byte.
// blocks [nb, nb+nwb): convert W1|W2|W3 fp32 -> fp16 instead.
__global__ void build_hist(const int* __restrict__ row, const int* __restrict__ col,
                           const float* __restrict__ ew, u64* __restrict__ el,
                           u32* __restrict__ ghist, int E, int N, int nb,
                           const float* __restrict__ W1, const float* __restrict__ W2,
                           const float* __restrict__ W3, __half* __restrict__ Wh,
                           int nw1, int nw2, int nw3) {
    const int b = blockIdx.x;
    if (b >= nb) {
        const int i = (b - nb) * 256 + threadIdx.x;
        const int tot = nw1 + nw2 + nw3;
        if (i < tot) {
            float v = (i < nw1) ? W1[i] : (i < nw1 + nw2 ? W2[i - nw1] : W3[i - nw1 - nw2]);
            Wh[i] = __float2half_rn(v);
        }
        return;
    }
    __shared__ u32 bin[256];
    bin[threadIdx.x] = 0;
    __syncthreads();
    const int total = E + N;
    const int base = b * SORT_ITEMS;
    const int end = min(base + SORT_ITEMS, total);
    for (int i = base + threadIdx.x; i < end; i += 256) {
        u64 e;
        if (i < E) {
            e = ((u64)(u32)col[i] << 48) | ((u64)(u32)row[i] << 32)
              | (u64)__float_as_uint(ew[i]);
        } else {
            int v = i - E;
            e = ((u64)(u32)v << 48) | ((u64)(u32)v << 32)
              | (u64)__float_as_uint(1.0f);
        }
        el[i] = e;
        atomicAdd(&bin[(u32)(e >> 56)], 1u);
    }
    __syncthreads();
    ghist[(size_t)threadIdx.x * nb + b] = bin[threadIdx.x];
}

// block d reduces ghist[d*nb .. d*nb+nb) -> dsum[d]   (R13 form)
__global__ void digit_sum(const u32* __restrict__ ghist, u32* __restrict__ dsum, int nb) {
    __shared__ u32 s[256];
    const int d = blockIdx.x;
    u32 acc = 0;
    for (int i = threadIdx.x; i < nb; i += 256) acc += ghist[(size_t)d * nb + i];
    s[threadIdx.x] = acc;
    __syncthreads();
    for (int off = 128; off > 0; off >>= 1) {
        if (threadIdx.x < off) s[threadIdx.x] += s[threadIdx.x + off];
        __syncthreads();
    }
    if (threadIdx.x == 0) dsum[d] = s[0];
}

// block d: re-scan dsum in LDS for its digit base, write dbase[d] (+[256]),
// then exclusive-scan its nb block-counts in place.   (R13 form)
__global__ void digit_scan(u32* __restrict__ ghist, const u32* __restrict__ dsum,
                           u32* __restrict__ dbase, int nb) {
    __shared__ u32 ds[256];
    __shared__ u32 s[256];
    const int d = blockIdx.x, t = threadIdx.x;
    ds[t] = dsum[t];
    __syncthreads();
    for (int off = 1; off < 256; off <<= 1) {
        u32 u = (t >= off) ? ds[t - off] : 0;
        __syncthreads();
        ds[t] += u;
        __syncthreads();
    }
    u32 carry = (d == 0) ? 0u : ds[d - 1];   // exclusive digit base
    if (t == 0) dbase[d] = carry;
    if (d == 255 && t == 0) dbase[256] = ds[255];
    for (int base = 0; base < nb; base += 256) {
        const int i = base + t;
        const u32 v = (i < nb) ? ghist[(size_t)d * nb + i] : 0;
        s[t] = v;
        __syncthreads();
        for (int off = 1; off < 256; off <<= 1) {
            u32 u = (t >= off) ? s[t - off] : 0;
            __syncthreads();
            s[t] += u;
            __syncthreads();
        }
        if (i < nb) ghist[(size_t)d * nb + i] = carry + s[t] - v;
        carry += s[255];
        __syncthreads();
    }
}

// pass 1 scatter, R16 form: LDS-staged coalesced flush.
__global__ __launch_bounds__(256) void p1_scatter(const u64* __restrict__ el,
                                                  const u32* __restrict__ ghist,
                                                  u64* __restrict__ out, int total, int nb) {
    __shared__ u32 gbase[256];
    __shared__ u32 lbase[256];
    __shared__ u32 lcur[256];
    __shared__ u64 buf[SORT_ITEMS];
    const int t = threadIdx.x;
    gbase[t] = ghist[(size_t)t * nb + blockIdx.x];
    lcur[t] = 0;                       // used as histogram first
    __syncthreads();
    const int base = blockIdx.x * SORT_ITEMS;
    const int end = min(base + SORT_ITEMS, total);
    const int cnt = end - base;

    u64 it[16];
    bool ok[16];
#pragma unroll
    for (int j = 0; j < 16; ++j) {
        const int i = base + t + j * 256;
        ok[j] = i < end;
        it[j] = ok[j] ? el[i] : 0;
        if (ok[j]) atomicAdd(&lcur[(u32)(it[j] >> 56)], 1u);
    }
    __syncthreads();
    const u32 v = lcur[t];
    lbase[t] = v;
    __syncthreads();
    for (int off = 1; off < 256; off <<= 1) {
        u32 u = (t >= off) ? lbase[t - off] : 0;
        __syncthreads();
        lbase[t] += u;
        __syncthreads();
    }
    const u32 excl = lbase[t] - v;     // exclusive local base for digit t
    __syncthreads();
    lbase[t] = excl;
    lcur[t] = excl;
    __syncthreads();
#pragma unroll
    for (int j = 0; j < 16; ++j) {
        if (ok[j]) {
            const u32 d = (u32)(it[j] >> 56);
            const u32 p = atomicAdd(&lcur[d], 1u);
            buf[p] = it[j];
        }
    }
    __syncthreads();
    for (int i = t; i < cnt; i += 256) {
        const u64 e = buf[i];
        const u32 d = (u32)(e >> 56);
        out[gbase[d] + i - lbase[d]] = e;
    }
}

// pass 2: one block per high-byte group; counting sort by low byte; emits
// offs[] and dinv[].   (R13/R16-exact 256-thread form)
__global__ void p2_sort(const u64* __restrict__ in, u64* __restrict__ out,
                        const u32* __restrict__ dbase,
                        int* __restrict__ offs, float* __restrict__ dinv, int n) {
    const int t = threadIdx.x;
    const int base = (int)dbase[blockIdx.x];
    const int size = (int)dbase[blockIdx.x + 1] - base;
    __shared__ u32 hist[256], cur[256], s[256];
    __shared__ float wsum[256];
    hist[t] = 0;
    wsum[t] = 0.f;
    __syncthreads();
    for (int i = t; i < size; i += 256)
        atomicAdd(&hist[(u32)(in[base + i] >> 48) & 0xFFu], 1u);
    __syncthreads();
    const u32 v = hist[t];
    s[t] = v;
    __syncthreads();
    for (int off = 1; off < 256; off <<= 1) {
        u32 u = (t >= off) ? s[t - off] : 0;
        __syncthreads();
        s[t] += u;
        __syncthreads();
    }
    const u32 mystart = (u32)base + s[t] - v;   // node (blockIdx*256+t)'s run start
    cur[t] = mystart;
    __syncthreads();
    for (int i = t; i < size; i += 256) {
        u64 e = in[base + i];
        u32 lo = (u32)(e >> 48) & 0xFFu;
        u32 p = atomicAdd(&cur[lo], 1u);
        out[p] = e;
        atomicAdd(&wsum[lo], __uint_as_float((u32)(e & 0xFFFFFFFFu)));
    }
    __syncthreads();
    const int node = blockIdx.x * 256 + t;
    if (node < n && v > 0) {
        offs[node] = (int)mystart;
        dinv[node] = rsqrtf(wsum[t]);
        if (node == n - 1) offs[n] = (int)(mystart + v);
    }
}

// ---------------- MFMA GEMM: C[n][o] = half(dinv[n] * sum_k A[n][k] * W[o][k]) ----------------

template <int BN, bool FP32IN>
__global__ __launch_bounds__(256) void mfma_gemm(const void* __restrict__ Ain,
                                                 const __half* __restrict__ Wh,
                                                 const float* __restrict__ dinv,
                                                 __half* __restrict__ C, int nrows) {
    constexpr int NT = BN / 16;
    const int wave = threadIdx.x >> 6;
    const int lane = threadIdx.x & 63;
    const int quad = lane >> 4;
    const int l16  = lane & 15;
    const int row0 = blockIdx.x * 64 + wave * 16;

    int arow = row0 + l16;
    if (arow > nrows - 1) arow = nrows - 1;

    floatx4 acc[NT] = {};

#pragma unroll
    for (int kc = 0; kc < 4; ++kc) {
        const int kof = kc * 32 + quad * 8;
        half8 af;
        if constexpr (FP32IN) {
            const float* ap = (const float*)Ain + (size_t)arow * K_DIM + kof;
            float4 f0 = *(const float4*)ap;
            float4 f1 = *(const float4*)(ap + 4);
            af[0] = (_Float16)f0.x; af[1] = (_Float16)f0.y;
            af[2] = (_Float16)f0.z; af[3] = (_Float16)f0.w;
            af[4] = (_Float16)f1.x; af[5] = (_Float16)f1.y;
            af[6] = (_Float16)f1.z; af[7] = (_Float16)f1.w;
        } else {
            af = *(const half8*)((const __half*)Ain + (size_t)arow * K_DIM + kof);
        }
#pragma unroll
        for (int ct = 0; ct < NT; ++ct) {
            half8 bf = *(const half8*)(Wh + (size_t)(ct * 16 + l16) * K_DIM + kof);
            acc[ct] = __builtin_amdgcn_mfma_f32_16x16x32_f16(af, bf, acc[ct], 0, 0, 0);
        }
    }

    // epilogue: D(row=quad*4+r, col=ct*16+l16)
    float dv[4];
    int grow[4];
    bool ok[4];
#pragma unroll
    for (int r = 0; r < 4; ++r) {
        grow[r] = row0 + quad * 4 + r;
        ok[r] = grow[r] < nrows;
        dv[r] = ok[r] ? dinv[grow[r]] : 0.f;
    }
#pragma unroll
    for (int ct = 0; ct < NT; ++ct) {
        const int colb = ct * 16 + l16;
#pragma unroll
        for (int r = 0; r < 4; ++r)
            if (ok[r])
                C[(size_t)grow[r] * BN + colb] = __float2half_rn(acc[ct][r] * dv[r]);
    }
}

// ---------------- aggregation: out[i] = relu(bias + dinv[i] * sum_e w_e * m[src_e]) ----------------
// m fp16. CSR entry = u64 as int2: .x = ew bits, .y & 0xFFFF = src row.
// R18: 16-deep gather batches (masked-16 head + full-16 body) WITH
// __launch_bounds__(256, 4) -> 128-VGPR cap so e[16]/f[16] stay live and all
// loads issue before any wait (R17 got squeezed to 32 VGPR and serialized).

template <int D, typename OUT>
__global__ __launch_bounds__(256, 4) void agg_kernel(
    const __half* __restrict__ m, const int* __restrict__ offs,
    const int2* __restrict__ csr, const float* __restrict__ dinv,
    const float* __restrict__ bias, OUT* __restrict__ out, int n) {
    const int wid = threadIdx.x >> 6;
    const int lane = threadIdx.x & 63;
    const int node = (blockIdx.x << 2) + wid;
    if (node >= n) return;
    const int beg = offs[node];
    const int end = offs[node + 1];
    const int cnt = end - beg;
    const int rem = cnt & 15;
    const __half2* mh = (const __half2*)m;   // row stride D/2 half2
    float acc0 = 0.f, acc1 = 0.f;

    if constexpr (D == 128) {
        int k = beg;
        if (rem) {
            int2 e[16];
            float2 f[16];
#pragma unroll
            for (int j = 0; j < 16; ++j) e[j] = csr[k + (j < rem ? j : 0)];
#pragma unroll
            for (int j = 0; j < 16; ++j)
                f[j] = __half22float2(mh[(size_t)(e[j].y & 0xFFFF) * 64 + lane]);
#pragma unroll
            for (int j = 0; j < 16; ++j) {
                float w = (j < rem) ? __int_as_float(e[j].x) : 0.f;
                acc0 = fmaf(w, f[j].x, acc0);
                acc1 = fmaf(w, f[j].y, acc1);
            }
            k += rem;
        }
        for (; k < end; k += 16) {
            int2 e[16];
            float2 f[16];
#pragma unroll
            for (int j = 0; j < 16; ++j) e[j] = csr[k + j];
#pragma unroll
            for (int j = 0; j < 16; ++j)
                f[j] = __half22float2(mh[(size_t)(e[j].y & 0xFFFF) * 64 + lane]);
#pragma unroll
            for (int j = 0; j < 16; ++j) {
                float w = __int_as_float(e[j].x);
                acc0 = fmaf(w, f[j].x, acc0);
                acc1 = fmaf(w, f[j].y, acc1);
            }
        }
        const float dv = dinv[node];
        const float2 bv = *(const float2*)(bias + 2 * lane);
        float ox = fmaxf(acc0 * dv + bv.x, 0.f);
        float oy = fmaxf(acc1 * dv + bv.y, 0.f);
        if constexpr (sizeof(OUT) == 2) {
            ((__half2*)out)[(size_t)node * 64 + lane] = __floats2half2_rn(ox, oy);
        } else {
            *(float2*)((float*)out + (size_t)node * 128 + 2 * lane) = make_float2(ox, oy);
        }
    } else {
        // D == 64: lanes 0-31 take even edges, 32-63 odd; feature pair (2sl, 2sl+1)
        const int half = lane >> 5;
        const int sl = lane & 31;
        int k = beg;
        if (rem) {
            int2 e[8];
            float2 f[8];
#pragma unroll
            for (int jj = 0; jj < 8; ++jj) {
                const int idx = 2 * jj + half;
                e[jj] = csr[k + (idx < rem ? idx : 0)];
            }
#pragma unroll
            for (int jj = 0; jj < 8; ++jj)
                f[jj] = __half22float2(mh[(size_t)(e[jj].y & 0xFFFF) * 32 + sl]);
#pragma unroll
            for (int jj = 0; jj < 8; ++jj) {
                const int idx = 2 * jj + half;
                float w = (idx < rem) ? __int_as_float(e[jj].x) : 0.f;
                acc0 = fmaf(w, f[jj].x, acc0);
                acc1 = fmaf(w, f[jj].y, acc1);
            }
            k += rem;
        }
        for (; k < end; k += 16) {
            int2 e[8];
            float2 f[8];
#pragma unroll
            for (int jj = 0; jj < 8; ++jj) e[jj] = csr[k + 2 * jj + half];
#pragma unroll
            for (int jj = 0; jj < 8; ++jj)
                f[jj] = __half22float2(mh[(size_t)(e[jj].y & 0xFFFF) * 32 + sl]);
#pragma unroll
            for (int jj = 0; jj < 8; ++jj) {
                float w = __int_as_float(e[jj].x);
                acc0 = fmaf(w, f[jj].x, acc0);
                acc1 = fmaf(w, f[jj].y, acc1);
            }
        }
        acc0 += __shfl_xor(acc0, 32);
        acc1 += __shfl_xor(acc1, 32);
        if (half == 0) {
            const float dv = dinv[node];
            const float2 bv = *(const float2*)(bias + 2 * sl);
            float ox = fmaxf(acc0 * dv + bv.x, 0.f);
            float oy = fmaxf(acc1 * dv + bv.y, 0.f);
            *(float2*)((float*)out + (size_t)node * 64 + 2 * sl) = make_float2(ox, oy);
        }
    }
}

// ---------------- launch ----------------

extern "C" void kernel_launch(void* const* d_in, const int* in_sizes, int n_in,
                              void* d_out, int out_size, void* d_ws, size_t ws_size,
                              hipStream_t stream) {
    const float* x  = (const float*)d_in[0];
    const int*   ei = (const int*)d_in[1];   // [2, E] int32
    const float* ew = (const float*)d_in[2];
    const float* W1 = (const float*)d_in[3];
    const float* b1 = (const float*)d_in[4];
    const float* W2 = (const float*)d_in[5];
    const float* b2 = (const float*)d_in[6];
    const float* W3 = (const float*)d_in[7];
    const float* b3 = (const float*)d_in[8];
    float* out = (float*)d_out;

    const int N = in_sizes[0] / K_DIM;      // 50000
    const int E = in_sizes[2];              // 800000
    const int* row = ei;                    // edge_index[0] (source)
    const int* col = ei + E;                // edge_index[1] (target / aggregation)

    const int total = E + N;                         // 850000
    const int nb = (total + SORT_ITEMS - 1) / SORT_ITEMS;   // 208
    const int ngroups = (N + 255) >> 8;              // 196 high-byte groups
    const int NW1 = 128 * 128, NW2 = 128 * 128, NW3 = 64 * 128;
    const int nwb = (NW1 + NW2 + NW3 + 255) / 256;   // 160 weight-convert blocks

    // workspace layout, 8B-aligned sections first
    u64* elA      = (u64*)d_ws;                                // total
    u64* elB      = elA + total;                               // total
    __half* m_buf = (__half*)(elB + total);                    // N*128 fp16
    __half* h_buf = m_buf + (size_t)N * K_DIM;                 // N*128 fp16
    __half* Wh    = h_buf + (size_t)N * K_DIM;                 // 40960 fp16
    u32* ghist    = (u32*)(Wh + NW1 + NW2 + NW3);              // 256*nb
    u32* dsum     = ghist + (size_t)256 * nb;                  // 256
    u32* dbase    = dsum + 256;                                // 257
    int* offs     = (int*)(dbase + 257);                       // N+1
    float* dinv   = (float*)(offs + N + 1);                    // N

    build_hist<<<nb + nwb, 256, 0, stream>>>(row, col, ew, elA, ghist, E, N, nb,
                                             W1, W2, W3, Wh, NW1, NW2, NW3);
    digit_sum<<<256, 256, 0, stream>>>(ghist, dsum, nb);
    digit_scan<<<256, 256, 0, stream>>>(ghist, dsum, dbase, nb);
    p1_scatter<<<nb, 256, 0, stream>>>(elA, ghist, elB, total, nb);
    p2_sort<<<ngroups, 256, 0, stream>>>(elB, elA, dbase, offs, dinv, N);

    const int gemm_blocks = (N + 63) / 64;
    const int agg_blocks = (N + 3) / 4;
    const int2* csr = (const int2*)elA;

    // layer 1: m = fp16(dinv * (x @ W1^T)) ; h = fp16(relu(dinv * agg(m) + b1))
    mfma_gemm<128, true><<<gemm_blocks, 256, 0, stream>>>(x, Wh, dinv, m_buf, N);
    agg_kernel<128, __half><<<agg_blocks, 256, 0, stream>>>(m_buf, offs, csr, dinv, b1, h_buf, N);
    // layer 2
    mfma_gemm<128, false><<<gemm_blocks, 256, 0, stream>>>(h_buf, Wh + NW1, dinv, m_buf, N);
    agg_kernel<128, __half><<<agg_blocks, 256, 0, stream>>>(m_buf, offs, csr, dinv, b2, h_buf, N);
    // layer 3: F_OUT=64, write d_out (fp32) directly
    mfma_gemm<64, false><<<gemm_blocks, 256, 0, stream>>>(h_buf, Wh + NW1 + NW2, dinv, b3 ? m_buf : m_buf, N);
    agg_kernel<64, float><<<agg_blocks, 256, 0, stream>>>(m_buf, offs, csr, dinv, b3, out, N);
}

// Round 6
// 282.097 us; speedup vs baseline: 1.0921x; 1.0921x over previous
//
#include <hip/hip_runtime.h>
#include <hip/hip_fp16.h>

// GraphEmbedNet: 3-layer GCN, N=50000, E=800000, F=128/128/64.
// R19 (R18 post-mortem: launch_bounds cap did NOT move VGPR_Count off 32 --
// compiler refuses to keep 16-deep load batches live; reg-array ILP is a
// dead end, 3rd data point). New agg structure gets edge-MLP from LANES:
// each lane loads half8 (16B), 16 lanes = full 128-feat row, so the wave's
// 4 quads gather 4 DIFFERENT edges per instruction. csr entries for the
// whole node (<=64) fetched in ONE coalesced per-lane load and distributed
// by __shfl -- kills the serial e->f chain. Independent gather rounds with
// ~50 VGPR footprint pipeline naturally. D=64 layer: 8 octets = 8 edges per
// instruction. deg>64 handled by rare fallback loop.
// Sort pipeline R16-exact (288.3us best config).

#define K_DIM 128
#define SORT_ITEMS 4096   // elements per pass-1 block

typedef unsigned long long u64;
typedef unsigned int u32;

using half8   = __attribute__((ext_vector_type(8))) _Float16;
using floatx4 = __attribute__((ext_vector_type(4))) float;

// ---------------- sort-based CSR build ----------------

// fused: pack edges + self-loops AND per-block 256-bin hist of high byte.
// blocks [nb, nb+nwb): convert W1|W2|W3 fp32 -> fp16 instead.
__global__ void build_hist(const int* __restrict__ row, const int* __restrict__ col,
                           const float* __restrict__ ew, u64* __restrict__ el,
                           u32* __restrict__ ghist, int E, int N, int nb,
                           const float* __restrict__ W1, const float* __restrict__ W2,
                           const float* __restrict__ W3, __half* __restrict__ Wh,
                           int nw1, int nw2, int nw3) {
    const int b = blockIdx.x;
    if (b >= nb) {
        const int i = (b - nb) * 256 + threadIdx.x;
        const int tot = nw1 + nw2 + nw3;
        if (i < tot) {
            float v = (i < nw1) ? W1[i] : (i < nw1 + nw2 ? W2[i - nw1] : W3[i - nw1 - nw2]);
            Wh[i] = __float2half_rn(v);
        }
        return;
    }
    __shared__ u32 bin[256];
    bin[threadIdx.x] = 0;
    __syncthreads();
    const int total = E + N;
    const int base = b * SORT_ITEMS;
    const int end = min(base + SORT_ITEMS, total);
    for (int i = base + threadIdx.x; i < end; i += 256) {
        u64 e;
        if (i < E) {
            e = ((u64)(u32)col[i] << 48) | ((u64)(u32)row[i] << 32)
              | (u64)__float_as_uint(ew[i]);
        } else {
            int v = i - E;
            e = ((u64)(u32)v << 48) | ((u64)(u32)v << 32)
              | (u64)__float_as_uint(1.0f);
        }
        el[i] = e;
        atomicAdd(&bin[(u32)(e >> 56)], 1u);
    }
    __syncthreads();
    ghist[(size_t)threadIdx.x * nb + b] = bin[threadIdx.x];
}

// block d reduces ghist[d*nb .. d*nb+nb) -> dsum[d]   (R13 form)
__global__ void digit_sum(const u32* __restrict__ ghist, u32* __restrict__ dsum, int nb) {
    __shared__ u32 s[256];
    const int d = blockIdx.x;
    u32 acc = 0;
    for (int i = threadIdx.x; i < nb; i += 256) acc += ghist[(size_t)d * nb + i];
    s[threadIdx.x] = acc;
    __syncthreads();
    for (int off = 128; off > 0; off >>= 1) {
        if (threadIdx.x < off) s[threadIdx.x] += s[threadIdx.x + off];
        __syncthreads();
    }
    if (threadIdx.x == 0) dsum[d] = s[0];
}

// block d: re-scan dsum in LDS for its digit base, write dbase[d] (+[256]),
// then exclusive-scan its nb block-counts in place.   (R13 form)
__global__ void digit_scan(u32* __restrict__ ghist, const u32* __restrict__ dsum,
                           u32* __restrict__ dbase, int nb) {
    __shared__ u32 ds[256];
    __shared__ u32 s[256];
    const int d = blockIdx.x, t = threadIdx.x;
    ds[t] = dsum[t];
    __syncthreads();
    for (int off = 1; off < 256; off <<= 1) {
        u32 u = (t >= off) ? ds[t - off] : 0;
        __syncthreads();
        ds[t] += u;
        __syncthreads();
    }
    u32 carry = (d == 0) ? 0u : ds[d - 1];   // exclusive digit base
    if (t == 0) dbase[d] = carry;
    if (d == 255 && t == 0) dbase[256] = ds[255];
    for (int base = 0; base < nb; base += 256) {
        const int i = base + t;
        const u32 v = (i < nb) ? ghist[(size_t)d * nb + i] : 0;
        s[t] = v;
        __syncthreads();
        for (int off = 1; off < 256; off <<= 1) {
            u32 u = (t >= off) ? s[t - off] : 0;
            __syncthreads();
            s[t] += u;
            __syncthreads();
        }
        if (i < nb) ghist[(size_t)d * nb + i] = carry + s[t] - v;
        carry += s[255];
        __syncthreads();
    }
}

// pass 1 scatter, R16 form: LDS-staged coalesced flush.
__global__ __launch_bounds__(256) void p1_scatter(const u64* __restrict__ el,
                                                  const u32* __restrict__ ghist,
                                                  u64* __restrict__ out, int total, int nb) {
    __shared__ u32 gbase[256];
    __shared__ u32 lbase[256];
    __shared__ u32 lcur[256];
    __shared__ u64 buf[SORT_ITEMS];
    const int t = threadIdx.x;
    gbase[t] = ghist[(size_t)t * nb + blockIdx.x];
    lcur[t] = 0;                       // used as histogram first
    __syncthreads();
    const int base = blockIdx.x * SORT_ITEMS;
    const int end = min(base + SORT_ITEMS, total);
    const int cnt = end - base;

    u64 it[16];
    bool ok[16];
#pragma unroll
    for (int j = 0; j < 16; ++j) {
        const int i = base + t + j * 256;
        ok[j] = i < end;
        it[j] = ok[j] ? el[i] : 0;
        if (ok[j]) atomicAdd(&lcur[(u32)(it[j] >> 56)], 1u);
    }
    __syncthreads();
    const u32 v = lcur[t];
    lbase[t] = v;
    __syncthreads();
    for (int off = 1; off < 256; off <<= 1) {
        u32 u = (t >= off) ? lbase[t - off] : 0;
        __syncthreads();
        lbase[t] += u;
        __syncthreads();
    }
    const u32 excl = lbase[t] - v;     // exclusive local base for digit t
    __syncthreads();
    lbase[t] = excl;
    lcur[t] = excl;
    __syncthreads();
#pragma unroll
    for (int j = 0; j < 16; ++j) {
        if (ok[j]) {
            const u32 d = (u32)(it[j] >> 56);
            const u32 p = atomicAdd(&lcur[d], 1u);
            buf[p] = it[j];
        }
    }
    __syncthreads();
    for (int i = t; i < cnt; i += 256) {
        const u64 e = buf[i];
        const u32 d = (u32)(e >> 56);
        out[gbase[d] + i - lbase[d]] = e;
    }
}

// pass 2: one block per high-byte group; counting sort by low byte; emits
// offs[] and dinv[].   (R13/R16-exact 256-thread form)
__global__ void p2_sort(const u64* __restrict__ in, u64* __restrict__ out,
                        const u32* __restrict__ dbase,
                        int* __restrict__ offs, float* __restrict__ dinv, int n) {
    const int t = threadIdx.x;
    const int base = (int)dbase[blockIdx.x];
    const int size = (int)dbase[blockIdx.x + 1] - base;
    __shared__ u32 hist[256], cur[256], s[256];
    __shared__ float wsum[256];
    hist[t] = 0;
    wsum[t] = 0.f;
    __syncthreads();
    for (int i = t; i < size; i += 256)
        atomicAdd(&hist[(u32)(in[base + i] >> 48) & 0xFFu], 1u);
    __syncthreads();
    const u32 v = hist[t];
    s[t] = v;
    __syncthreads();
    for (int off = 1; off < 256; off <<= 1) {
        u32 u = (t >= off) ? s[t - off] : 0;
        __syncthreads();
        s[t] += u;
        __syncthreads();
    }
    const u32 mystart = (u32)base + s[t] - v;   // node (blockIdx*256+t)'s run start
    cur[t] = mystart;
    __syncthreads();
    for (int i = t; i < size; i += 256) {
        u64 e = in[base + i];
        u32 lo = (u32)(e >> 48) & 0xFFu;
        u32 p = atomicAdd(&cur[lo], 1u);
        out[p] = e;
        atomicAdd(&wsum[lo], __uint_as_float((u32)(e & 0xFFFFFFFFu)));
    }
    __syncthreads();
    const int node = blockIdx.x * 256 + t;
    if (node < n && v > 0) {
        offs[node] = (int)mystart;
        dinv[node] = rsqrtf(wsum[t]);
        if (node == n - 1) offs[n] = (int)(mystart + v);
    }
}

// ---------------- MFMA GEMM: C[n][o] = half(dinv[n] * sum_k A[n][k] * W[o][k]) ----------------

template <int BN, bool FP32IN>
__global__ __launch_bounds__(256) void mfma_gemm(const void* __restrict__ Ain,
                                                 const __half* __restrict__ Wh,
                                                 const float* __restrict__ dinv,
                                                 __half* __restrict__ C, int nrows) {
    constexpr int NT = BN / 16;
    const int wave = threadIdx.x >> 6;
    const int lane = threadIdx.x & 63;
    const int quad = lane >> 4;
    const int l16  = lane & 15;
    const int row0 = blockIdx.x * 64 + wave * 16;

    int arow = row0 + l16;
    if (arow > nrows - 1) arow = nrows - 1;

    floatx4 acc[NT] = {};

#pragma unroll
    for (int kc = 0; kc < 4; ++kc) {
        const int kof = kc * 32 + quad * 8;
        half8 af;
        if constexpr (FP32IN) {
            const float* ap = (const float*)Ain + (size_t)arow * K_DIM + kof;
            float4 f0 = *(const float4*)ap;
            float4 f1 = *(const float4*)(ap + 4);
            af[0] = (_Float16)f0.x; af[1] = (_Float16)f0.y;
            af[2] = (_Float16)f0.z; af[3] = (_Float16)f0.w;
            af[4] = (_Float16)f1.x; af[5] = (_Float16)f1.y;
            af[6] = (_Float16)f1.z; af[7] = (_Float16)f1.w;
        } else {
            af = *(const half8*)((const __half*)Ain + (size_t)arow * K_DIM + kof);
        }
#pragma unroll
        for (int ct = 0; ct < NT; ++ct) {
            half8 bf = *(const half8*)(Wh + (size_t)(ct * 16 + l16) * K_DIM + kof);
            acc[ct] = __builtin_amdgcn_mfma_f32_16x16x32_f16(af, bf, acc[ct], 0, 0, 0);
        }
    }

    // epilogue: D(row=quad*4+r, col=ct*16+l16)
    float dv[4];
    int grow[4];
    bool ok[4];
#pragma unroll
    for (int r = 0; r < 4; ++r) {
        grow[r] = row0 + quad * 4 + r;
        ok[r] = grow[r] < nrows;
        dv[r] = ok[r] ? dinv[grow[r]] : 0.f;
    }
#pragma unroll
    for (int ct = 0; ct < NT; ++ct) {
        const int colb = ct * 16 + l16;
#pragma unroll
        for (int r = 0; r < 4; ++r)
            if (ok[r])
                C[(size_t)grow[r] * BN + colb] = __float2half_rn(acc[ct][r] * dv[r]);
    }
}

// ---------------- aggregation: out[i] = relu(bias + dinv[i] * sum_e w_e * m[src_e]) ----------------
// R19 quad-parallel form. One wave per node. CSR entry int2: .x = ew bits,
// .y & 0xFFFF = src row.
// D=128: lane loads half8 (16B); 16 lanes (l16) cover the row; 4 quads
//   gather 4 DIFFERENT edges per instruction. csr entries for the node
//   (<=64) come from ONE coalesced per-lane load, distributed via __shfl.
//   Cross-quad reduce: shfl_xor 16,32. deg>64: rare per-quad fallback loop.
// D=64: same with 8 octets (8 edges/instruction), reduce shfl_xor 8,16,32.

template <int D, typename OUT>
__global__ __launch_bounds__(256) void agg_kernel(
    const __half* __restrict__ m, const int* __restrict__ offs,
    const int2* __restrict__ csr, const float* __restrict__ dinv,
    const float* __restrict__ bias, OUT* __restrict__ out, int n) {
    const int wid = threadIdx.x >> 6;
    const int lane = threadIdx.x & 63;
    const int node = (blockIdx.x << 2) + wid;
    if (node >= n) return;
    const int beg = offs[node];
    const int end = offs[node + 1];
    const int cnt = end - beg;          // >= 1 (self-loop)
    const half8* mrow = (const half8*)m;

    // one coalesced load fetches up to 64 csr entries for this node
    const int2 ev = csr[beg + min(lane, cnt - 1)];
    const float wv = (lane < cnt) ? __int_as_float(ev.x) : 0.f;
    const int   sv = ev.y & 0xFFFF;
    const int nr = min(cnt, 64);

    float acc[8] = {0.f, 0.f, 0.f, 0.f, 0.f, 0.f, 0.f, 0.f};

    if constexpr (D == 128) {
        const int quad = lane >> 4;
        const int l16  = lane & 15;
        for (int r = 0; r * 4 < nr; ++r) {
            const int j = r * 4 + quad;
            const bool ok = j < nr;
            float w = __shfl(wv, j);
            int   s = __shfl(sv, j);
            w = ok ? w : 0.f;
            s = ok ? s : 0;
            half8 hv = mrow[(size_t)s * 16 + l16];
#pragma unroll
            for (int i = 0; i < 8; ++i)
                acc[i] = fmaf(w, (float)hv[i], acc[i]);
        }
        // rare: degree > 64 tail, per-quad strided
        for (int k = beg + 64 + quad; k < end; k += 4) {
            const int2 e0 = csr[k];
            const float w0 = __int_as_float(e0.x);
            half8 hv = mrow[(size_t)(e0.y & 0xFFFF) * 16 + l16];
#pragma unroll
            for (int i = 0; i < 8; ++i)
                acc[i] = fmaf(w0, (float)hv[i], acc[i]);
        }
#pragma unroll
        for (int i = 0; i < 8; ++i) {
            acc[i] += __shfl_xor(acc[i], 16);
            acc[i] += __shfl_xor(acc[i], 32);
        }
        if (quad == 0) {
            const float dv = dinv[node];
            const float4 b0 = *(const float4*)(bias + l16 * 8);
            const float4 b1 = *(const float4*)(bias + l16 * 8 + 4);
            const float bb[8] = {b0.x, b0.y, b0.z, b0.w, b1.x, b1.y, b1.z, b1.w};
            half8 ho;
#pragma unroll
            for (int i = 0; i < 8; ++i)
                ho[i] = (_Float16)fmaxf(acc[i] * dv + bb[i], 0.f);
            *(half8*)((__half*)out + (size_t)node * 128 + l16 * 8) = ho;
        }
    } else {
        // D == 64
        const int oct = lane >> 3;
        const int l8  = lane & 7;
        for (int r = 0; r * 8 < nr; ++r) {
            const int j = r * 8 + oct;
            const bool ok = j < nr;
            float w = __shfl(wv, j);
            int   s = __shfl(sv, j);
            w = ok ? w : 0.f;
            s = ok ? s : 0;
            half8 hv = mrow[(size_t)s * 8 + l8];
#pragma unroll
            for (int i = 0; i < 8; ++i)
                acc[i] = fmaf(w, (float)hv[i], acc[i]);
        }
        for (int k = beg + 64 + oct; k < end; k += 8) {
            const int2 e0 = csr[k];
            const float w0 = __int_as_float(e0.x);
            half8 hv = mrow[(size_t)(e0.y & 0xFFFF) * 8 + l8];
#pragma unroll
            for (int i = 0; i < 8; ++i)
                acc[i] = fmaf(w0, (float)hv[i], acc[i]);
        }
#pragma unroll
        for (int i = 0; i < 8; ++i) {
            acc[i] += __shfl_xor(acc[i], 8);
            acc[i] += __shfl_xor(acc[i], 16);
            acc[i] += __shfl_xor(acc[i], 32);
        }
        if (oct == 0) {
            const float dv = dinv[node];
            const float4 b0 = *(const float4*)(bias + l8 * 8);
            const float4 b1 = *(const float4*)(bias + l8 * 8 + 4);
            float4 v0, v1;
            v0.x = fmaxf(acc[0] * dv + b0.x, 0.f);
            v0.y = fmaxf(acc[1] * dv + b0.y, 0.f);
            v0.z = fmaxf(acc[2] * dv + b0.z, 0.f);
            v0.w = fmaxf(acc[3] * dv + b0.w, 0.f);
            v1.x = fmaxf(acc[4] * dv + b1.x, 0.f);
            v1.y = fmaxf(acc[5] * dv + b1.y, 0.f);
            v1.z = fmaxf(acc[6] * dv + b1.z, 0.f);
            v1.w = fmaxf(acc[7] * dv + b1.w, 0.f);
            float* op = (float*)out + (size_t)node * 64 + l8 * 8;
            *(float4*)op = v0;
            *(float4*)(op + 4) = v1;
        }
    }
}

// ---------------- launch ----------------

extern "C" void kernel_launch(void* const* d_in, const int* in_sizes, int n_in,
                              void* d_out, int out_size, void* d_ws, size_t ws_size,
                              hipStream_t stream) {
    const float* x  = (const float*)d_in[0];
    const int*   ei = (const int*)d_in[1];   // [2, E] int32
    const float* ew = (const float*)d_in[2];
    const float* W1 = (const float*)d_in[3];
    const float* b1 = (const float*)d_in[4];
    const float* W2 = (const float*)d_in[5];
    const float* b2 = (const float*)d_in[6];
    const float* W3 = (const float*)d_in[7];
    const float* b3 = (const float*)d_in[8];
    float* out = (float*)d_out;

    const int N = in_sizes[0] / K_DIM;      // 50000
    const int E = in_sizes[2];              // 800000
    const int* row = ei;                    // edge_index[0] (source)
    const int* col = ei + E;                // edge_index[1] (target / aggregation)

    const int total = E + N;                         // 850000
    const int nb = (total + SORT_ITEMS - 1) / SORT_ITEMS;   // 208
    const int ngroups = (N + 255) >> 8;              // 196 high-byte groups
    const int NW1 = 128 * 128, NW2 = 128 * 128, NW3 = 64 * 128;
    const int nwb = (NW1 + NW2 + NW3 + 255) / 256;   // 160 weight-convert blocks

    // workspace layout, 8B-aligned sections first
    u64* elA      = (u64*)d_ws;                                // total
    u64* elB      = elA + total;                               // total
    __half* m_buf = (__half*)(elB + total);                    // N*128 fp16
    __half* h_buf = m_buf + (size_t)N * K_DIM;                 // N*128 fp16
    __half* Wh    = h_buf + (size_t)N * K_DIM;                 // 40960 fp16
    u32* ghist    = (u32*)(Wh + NW1 + NW2 + NW3);              // 256*nb
    u32* dsum     = ghist + (size_t)256 * nb;                  // 256
    u32* dbase    = dsum + 256;                                // 257
    int* offs     = (int*)(dbase + 257);                       // N+1
    float* dinv   = (float*)(offs + N + 1);                    // N

    build_hist<<<nb + nwb, 256, 0, stream>>>(row, col, ew, elA, ghist, E, N, nb,
                                             W1, W2, W3, Wh, NW1, NW2, NW3);
    digit_sum<<<256, 256, 0, stream>>>(ghist, dsum, nb);
    digit_scan<<<256, 256, 0, stream>>>(ghist, dsum, dbase, nb);
    p1_scatter<<<nb, 256, 0, stream>>>(elA, ghist, elB, total, nb);
    p2_sort<<<ngroups, 256, 0, stream>>>(elB, elA, dbase, offs, dinv, N);

    const int gemm_blocks = (N + 63) / 64;
    const int agg_blocks = (N + 3) / 4;
    const int2* csr = (const int2*)elA;

    // layer 1: m = fp16(dinv * (x @ W1^T)) ; h = fp16(relu(dinv * agg(m) + b1))
    mfma_gemm<128, true><<<gemm_blocks, 256, 0, stream>>>(x, Wh, dinv, m_buf, N);
    agg_kernel<128, __half><<<agg_blocks, 256, 0, stream>>>(m_buf, offs, csr, dinv, b1, h_buf, N);
    // layer 2
    mfma_gemm<128, false><<<gemm_blocks, 256, 0, stream>>>(h_buf, Wh + NW1, dinv, m_buf, N);
    agg_kernel<128, __half><<<agg_blocks, 256, 0, stream>>>(m_buf, offs, csr, dinv, b2, h_buf, N);
    // layer 3: F_OUT=64, write d_out (fp32) directly
    mfma_gemm<64, false><<<gemm_blocks, 256, 0, stream>>>(h_buf, Wh + NW1 + NW2, dinv, m_buf, N);
    agg_kernel<64, float><<<agg_blocks, 256, 0, stream>>>(m_buf, offs, csr, dinv, b3, out, N);
}

// Round 7
// 274.640 us; speedup vs baseline: 1.1218x; 1.0272x over previous
//
#include <hip/hip_runtime.h>
#include <hip/hip_fp16.h>

// GraphEmbedNet: 3-layer GCN, N=50000, E=800000, F=128/128/64.
// R20 (on R19 = 282.1us best):
// (a) RE-ADD quarter-private p2_sort@1024 (R17-verbatim, refcheck-passed).
//     Evidence: R17 vs R18 differ ONLY in p2 form (agg counters byte-equal),
//     301.5 vs 308.1 -> p2-quarter = -6.6us. R18's revert mis-attributed it.
// (b) Fold dinv[src] into agg (one L2-hot 4B load in the per-lane header,
//     parallel to the m-gathers, zero extra serial depth) so mfma_gemm no
//     longer needs dinv. gemm L1 then depends only on x/Wh -> its blocks are
//     MERGED into the p2 launch (blocks >= ngroups run a 16-wave variant of
//     the same MFMA tile). p2 is latency-bound at 196 blocks; gemm fills the
//     idle CUs. 11 -> 10 dispatches.
// Numerics: m_raw stored unscaled in fp16 -- rounding is scale-invariant,
// ew*dinv_s applied in fp32; same error budget as before.

#define K_DIM 128
#define SORT_ITEMS 4096   // elements per pass-1 block

typedef unsigned long long u64;
typedef unsigned int u32;

using half8   = __attribute__((ext_vector_type(8))) _Float16;
using floatx4 = __attribute__((ext_vector_type(4))) float;

// ---------------- sort-based CSR build ----------------

// fused: pack edges + self-loops AND per-block 256-bin hist of high byte.
// blocks [nb, nb+nwb): convert W1|W2|W3 fp32 -> fp16 instead.
__global__ void build_hist(const int* __restrict__ row, const int* __restrict__ col,
                           const float* __restrict__ ew, u64* __restrict__ el,
                           u32* __restrict__ ghist, int E, int N, int nb,
                           const float* __restrict__ W1, const float* __restrict__ W2,
                           const float* __restrict__ W3, __half* __restrict__ Wh,
                           int nw1, int nw2, int nw3) {
    const int b = blockIdx.x;
    if (b >= nb) {
        const int i = (b - nb) * 256 + threadIdx.x;
        const int tot = nw1 + nw2 + nw3;
        if (i < tot) {
            float v = (i < nw1) ? W1[i] : (i < nw1 + nw2 ? W2[i - nw1] : W3[i - nw1 - nw2]);
            Wh[i] = __float2half_rn(v);
        }
        return;
    }
    __shared__ u32 bin[256];
    bin[threadIdx.x] = 0;
    __syncthreads();
    const int total = E + N;
    const int base = b * SORT_ITEMS;
    const int end = min(base + SORT_ITEMS, total);
    for (int i = base + threadIdx.x; i < end; i += 256) {
        u64 e;
        if (i < E) {
            e = ((u64)(u32)col[i] << 48) | ((u64)(u32)row[i] << 32)
              | (u64)__float_as_uint(ew[i]);
        } else {
            int v = i - E;
            e = ((u64)(u32)v << 48) | ((u64)(u32)v << 32)
              | (u64)__float_as_uint(1.0f);
        }
        el[i] = e;
        atomicAdd(&bin[(u32)(e >> 56)], 1u);
    }
    __syncthreads();
    ghist[(size_t)threadIdx.x * nb + b] = bin[threadIdx.x];
}

// block d reduces ghist[d*nb .. d*nb+nb) -> dsum[d]   (R13 form)
__global__ void digit_sum(const u32* __restrict__ ghist, u32* __restrict__ dsum, int nb) {
    __shared__ u32 s[256];
    const int d = blockIdx.x;
    u32 acc = 0;
    for (int i = threadIdx.x; i < nb; i += 256) acc += ghist[(size_t)d * nb + i];
    s[threadIdx.x] = acc;
    __syncthreads();
    for (int off = 128; off > 0; off >>= 1) {
        if (threadIdx.x < off) s[threadIdx.x] += s[threadIdx.x + off];
        __syncthreads();
    }
    if (threadIdx.x == 0) dsum[d] = s[0];
}

// block d: re-scan dsum in LDS for its digit base, write dbase[d] (+[256]),
// then exclusive-scan its nb block-counts in place.   (R13 form)
__global__ void digit_scan(u32* __restrict__ ghist, const u32* __restrict__ dsum,
                           u32* __restrict__ dbase, int nb) {
    __shared__ u32 ds[256];
    __shared__ u32 s[256];
    const int d = blockIdx.x, t = threadIdx.x;
    ds[t] = dsum[t];
    __syncthreads();
    for (int off = 1; off < 256; off <<= 1) {
        u32 u = (t >= off) ? ds[t - off] : 0;
        __syncthreads();
        ds[t] += u;
        __syncthreads();
    }
    u32 carry = (d == 0) ? 0u : ds[d - 1];   // exclusive digit base
    if (t == 0) dbase[d] = carry;
    if (d == 255 && t == 0) dbase[256] = ds[255];
    for (int base = 0; base < nb; base += 256) {
        const int i = base + t;
        const u32 v = (i < nb) ? ghist[(size_t)d * nb + i] : 0;
        s[t] = v;
        __syncthreads();
        for (int off = 1; off < 256; off <<= 1) {
            u32 u = (t >= off) ? s[t - off] : 0;
            __syncthreads();
            s[t] += u;
            __syncthreads();
        }
        if (i < nb) ghist[(size_t)d * nb + i] = carry + s[t] - v;
        carry += s[255];
        __syncthreads();
    }
}

// pass 1 scatter, R16 form: LDS-staged coalesced flush.
__global__ __launch_bounds__(256) void p1_scatter(const u64* __restrict__ el,
                                                  const u32* __restrict__ ghist,
                                                  u64* __restrict__ out, int total, int nb) {
    __shared__ u32 gbase[256];
    __shared__ u32 lbase[256];
    __shared__ u32 lcur[256];
    __shared__ u64 buf[SORT_ITEMS];
    const int t = threadIdx.x;
    gbase[t] = ghist[(size_t)t * nb + blockIdx.x];
    lcur[t] = 0;                       // used as histogram first
    __syncthreads();
    const int base = blockIdx.x * SORT_ITEMS;
    const int end = min(base + SORT_ITEMS, total);
    const int cnt = end - base;

    u64 it[16];
    bool ok[16];
#pragma unroll
    for (int j = 0; j < 16; ++j) {
        const int i = base + t + j * 256;
        ok[j] = i < end;
        it[j] = ok[j] ? el[i] : 0;
        if (ok[j]) atomicAdd(&lcur[(u32)(it[j] >> 56)], 1u);
    }
    __syncthreads();
    const u32 v = lcur[t];
    lbase[t] = v;
    __syncthreads();
    for (int off = 1; off < 256; off <<= 1) {
        u32 u = (t >= off) ? lbase[t - off] : 0;
        __syncthreads();
        lbase[t] += u;
        __syncthreads();
    }
    const u32 excl = lbase[t] - v;     // exclusive local base for digit t
    __syncthreads();
    lbase[t] = excl;
    lcur[t] = excl;
    __syncthreads();
#pragma unroll
    for (int j = 0; j < 16; ++j) {
        if (ok[j]) {
            const u32 d = (u32)(it[j] >> 56);
            const u32 p = atomicAdd(&lcur[d], 1u);
            buf[p] = it[j];
        }
    }
    __syncthreads();
    for (int i = t; i < cnt; i += 256) {
        const u64 e = buf[i];
        const u32 d = (u32)(e >> 56);
        out[gbase[d] + i - lbase[d]] = e;
    }
}

// ---------------- merged pass 2 + layer-1 GEMM ----------------
// blocks [0, ngroups): R17-verbatim quarter-private counting sort (1024 thr,
//   per-quarter hist/cur/wsum -> 256-thread-level LDS contention, 4x waves).
// blocks [ngroups, ...): 16-wave MFMA GEMM m_raw = fp16(x @ W1^T), 256 rows
//   per block (wave w -> rows gb*256 + w*16). No dinv (folded into agg).
__global__ __launch_bounds__(1024) void p2_gemm(
        const u64* __restrict__ in, u64* __restrict__ out,
        const u32* __restrict__ dbase,
        int* __restrict__ offs, float* __restrict__ dinv, int n, int ngroups,
        const float* __restrict__ x, const __half* __restrict__ Wh,
        __half* __restrict__ C) {
    if ((int)blockIdx.x < ngroups) {
        // ---- p2 quarter-private sort ----
        const int t = threadIdx.x;
        const int q = t >> 8;          // quarter 0..3
        const int b = t & 255;
        const int base = (int)dbase[blockIdx.x];
        const int size = (int)dbase[blockIdx.x + 1] - base;
        __shared__ u32 hist[4][256];
        __shared__ u32 cur[4][256];
        __shared__ u32 s[256];
        __shared__ float wsum[4][256];
        hist[q][b] = 0;
        wsum[q][b] = 0.f;
        __syncthreads();
        for (int i = t; i < size; i += 1024)
            atomicAdd(&hist[q][(u32)(in[base + i] >> 48) & 0xFFu], 1u);
        __syncthreads();
        u32 v = 0;
        if (t < 256) {
            v = hist[0][b] + hist[1][b] + hist[2][b] + hist[3][b];
            s[b] = v;
        }
        __syncthreads();
        for (int off = 1; off < 256; off <<= 1) {
            u32 u = (t < 256 && b >= off) ? s[b - off] : 0;
            __syncthreads();
            if (t < 256) s[b] += u;
            __syncthreads();
        }
        u32 mystart = 0;
        if (t < 256) {
            mystart = (u32)base + s[b] - v;   // node (blockIdx*256+b)'s run start
            u32 c = mystart;
            cur[0][b] = c; c += hist[0][b];
            cur[1][b] = c; c += hist[1][b];
            cur[2][b] = c; c += hist[2][b];
            cur[3][b] = c;
        }
        __syncthreads();
        for (int i = t; i < size; i += 1024) {
            u64 e = in[base + i];
            u32 lo = (u32)(e >> 48) & 0xFFu;
            u32 p = atomicAdd(&cur[q][lo], 1u);
            out[p] = e;
            atomicAdd(&wsum[q][lo], __uint_as_float((u32)(e & 0xFFFFFFFFu)));
        }
        __syncthreads();
        const int node = blockIdx.x * 256 + b;
        if (t < 256 && node < n && v > 0) {
            offs[node] = (int)mystart;
            dinv[node] = rsqrtf(wsum[0][b] + wsum[1][b] + wsum[2][b] + wsum[3][b]);
            if (node == n - 1) offs[n] = (int)(mystart + v);
        }
    } else {
        // ---- layer-1 GEMM tile: 16 waves x 16 rows, BN=128, fp32 input ----
        const int gb = blockIdx.x - ngroups;
        const int wave = threadIdx.x >> 6;
        const int lane = threadIdx.x & 63;
        const int quad = lane >> 4;
        const int l16  = lane & 15;
        const int row0 = gb * 256 + wave * 16;

        int arow = row0 + l16;
        if (arow > n - 1) arow = n - 1;

        floatx4 acc[8] = {};
#pragma unroll
        for (int kc = 0; kc < 4; ++kc) {
            const int kof = kc * 32 + quad * 8;
            const float* ap = x + (size_t)arow * K_DIM + kof;
            float4 f0 = *(const float4*)ap;
            float4 f1 = *(const float4*)(ap + 4);
            half8 af;
            af[0] = (_Float16)f0.x; af[1] = (_Float16)f0.y;
            af[2] = (_Float16)f0.z; af[3] = (_Float16)f0.w;
            af[4] = (_Float16)f1.x; af[5] = (_Float16)f1.y;
            af[6] = (_Float16)f1.z; af[7] = (_Float16)f1.w;
#pragma unroll
            for (int ct = 0; ct < 8; ++ct) {
                half8 bf = *(const half8*)(Wh + (size_t)(ct * 16 + l16) * K_DIM + kof);
                acc[ct] = __builtin_amdgcn_mfma_f32_16x16x32_f16(af, bf, acc[ct], 0, 0, 0);
            }
        }
        int grow[4];
        bool ok[4];
#pragma unroll
        for (int r = 0; r < 4; ++r) {
            grow[r] = row0 + quad * 4 + r;
            ok[r] = grow[r] < n;
        }
#pragma unroll
        for (int ct = 0; ct < 8; ++ct) {
            const int colb = ct * 16 + l16;
#pragma unroll
            for (int r = 0; r < 4; ++r)
                if (ok[r])
                    C[(size_t)grow[r] * 128 + colb] = __float2half_rn(acc[ct][r]);
        }
    }
}

// ---------------- MFMA GEMM (layers 2,3): C[n][o] = half(sum_k A[n][k]*W[o][k]) ----------------
// no dinv scaling (folded into agg).

template <int BN>
__global__ __launch_bounds__(256) void mfma_gemm(const __half* __restrict__ Ain,
                                                 const __half* __restrict__ Wh,
                                                 __half* __restrict__ C, int nrows) {
    constexpr int NT = BN / 16;
    const int wave = threadIdx.x >> 6;
    const int lane = threadIdx.x & 63;
    const int quad = lane >> 4;
    const int l16  = lane & 15;
    const int row0 = blockIdx.x * 64 + wave * 16;

    int arow = row0 + l16;
    if (arow > nrows - 1) arow = nrows - 1;

    floatx4 acc[NT] = {};

#pragma unroll
    for (int kc = 0; kc < 4; ++kc) {
        const int kof = kc * 32 + quad * 8;
        half8 af = *(const half8*)(Ain + (size_t)arow * K_DIM + kof);
#pragma unroll
        for (int ct = 0; ct < NT; ++ct) {
            half8 bf = *(const half8*)(Wh + (size_t)(ct * 16 + l16) * K_DIM + kof);
            acc[ct] = __builtin_amdgcn_mfma_f32_16x16x32_f16(af, bf, acc[ct], 0, 0, 0);
        }
    }

    int grow[4];
    bool ok[4];
#pragma unroll
    for (int r = 0; r < 4; ++r) {
        grow[r] = row0 + quad * 4 + r;
        ok[r] = grow[r] < nrows;
    }
#pragma unroll
    for (int ct = 0; ct < NT; ++ct) {
        const int colb = ct * 16 + l16;
#pragma unroll
        for (int r = 0; r < 4; ++r)
            if (ok[r])
                C[(size_t)grow[r] * BN + colb] = __float2half_rn(acc[ct][r]);
    }
}

// ---------------- aggregation ----------------
// out[i] = relu(bias + dinv[i] * sum_e (ew_e * dinv[src_e]) * m_raw[src_e])
// R19 quad-parallel form + dinv[src] folded into the per-lane header weight
// (one L2-hot 4B load, parallel to the m gathers; zero extra serial depth).

template <int D, typename OUT>
__global__ __launch_bounds__(256) void agg_kernel(
    const __half* __restrict__ m, const int* __restrict__ offs,
    const int2* __restrict__ csr, const float* __restrict__ dinv,
    const float* __restrict__ bias, OUT* __restrict__ out, int n) {
    const int wid = threadIdx.x >> 6;
    const int lane = threadIdx.x & 63;
    const int node = (blockIdx.x << 2) + wid;
    if (node >= n) return;
    const int beg = offs[node];
    const int end = offs[node + 1];
    const int cnt = end - beg;          // >= 1 (self-loop)
    const half8* mrow = (const half8*)m;

    // one coalesced load fetches up to 64 csr entries for this node
    const int2 ev = csr[beg + min(lane, cnt - 1)];
    const int   sv = ev.y & 0xFFFF;
    const float ds = dinv[sv];                      // L2-hot (200KB table)
    const float wv = (lane < cnt) ? __int_as_float(ev.x) * ds : 0.f;
    const int nr = min(cnt, 64);

    float acc[8] = {0.f, 0.f, 0.f, 0.f, 0.f, 0.f, 0.f, 0.f};

    if constexpr (D == 128) {
        const int quad = lane >> 4;
        const int l16  = lane & 15;
        for (int r = 0; r * 4 < nr; ++r) {
            const int j = r * 4 + quad;
            const bool ok = j < nr;
            float w = __shfl(wv, j);
            int   s = __shfl(sv, j);
            w = ok ? w : 0.f;
            s = ok ? s : 0;
            half8 hv = mrow[(size_t)s * 16 + l16];
#pragma unroll
            for (int i = 0; i < 8; ++i)
                acc[i] = fmaf(w, (float)hv[i], acc[i]);
        }
        // rare: degree > 64 tail, per-quad strided
        for (int k = beg + 64 + quad; k < end; k += 4) {
            const int2 e0 = csr[k];
            const int  s0 = e0.y & 0xFFFF;
            const float w0 = __int_as_float(e0.x) * dinv[s0];
            half8 hv = mrow[(size_t)s0 * 16 + l16];
#pragma unroll
            for (int i = 0; i < 8; ++i)
                acc[i] = fmaf(w0, (float)hv[i], acc[i]);
        }
#pragma unroll
        for (int i = 0; i < 8; ++i) {
            acc[i] += __shfl_xor(acc[i], 16);
            acc[i] += __shfl_xor(acc[i], 32);
        }
        if (quad == 0) {
            const float dv = dinv[node];
            const float4 b0 = *(const float4*)(bias + l16 * 8);
            const float4 b1 = *(const float4*)(bias + l16 * 8 + 4);
            const float bb[8] = {b0.x, b0.y, b0.z, b0.w, b1.x, b1.y, b1.z, b1.w};
            half8 ho;
#pragma unroll
            for (int i = 0; i < 8; ++i)
                ho[i] = (_Float16)fmaxf(acc[i] * dv + bb[i], 0.f);
            *(half8*)((__half*)out + (size_t)node * 128 + l16 * 8) = ho;
        }
    } else {
        // D == 64
        const int oct = lane >> 3;
        const int l8  = lane & 7;
        for (int r = 0; r * 8 < nr; ++r) {
            const int j = r * 8 + oct;
            const bool ok = j < nr;
            float w = __shfl(wv, j);
            int   s = __shfl(sv, j);
            w = ok ? w : 0.f;
            s = ok ? s : 0;
            half8 hv = mrow[(size_t)s * 8 + l8];
#pragma unroll
            for (int i = 0; i < 8; ++i)
                acc[i] = fmaf(w, (float)hv[i], acc[i]);
        }
        for (int k = beg + 64 + oct; k < end; k += 8) {
            const int2 e0 = csr[k];
            const int  s0 = e0.y & 0xFFFF;
            const float w0 = __int_as_float(e0.x) * dinv[s0];
            half8 hv = mrow[(size_t)s0 * 8 + l8];
#pragma unroll
            for (int i = 0; i < 8; ++i)
                acc[i] = fmaf(w0, (float)hv[i], acc[i]);
        }
#pragma unroll
        for (int i = 0; i < 8; ++i) {
            acc[i] += __shfl_xor(acc[i], 8);
            acc[i] += __shfl_xor(acc[i], 16);
            acc[i] += __shfl_xor(acc[i], 32);
        }
        if (oct == 0) {
            const float dv = dinv[node];
            const float4 b0 = *(const float4*)(bias + l8 * 8);
            const float4 b1 = *(const float4*)(bias + l8 * 8 + 4);
            float4 v0, v1;
            v0.x = fmaxf(acc[0] * dv + b0.x, 0.f);
            v0.y = fmaxf(acc[1] * dv + b0.y, 0.f);
            v0.z = fmaxf(acc[2] * dv + b0.z, 0.f);
            v0.w = fmaxf(acc[3] * dv + b0.w, 0.f);
            v1.x = fmaxf(acc[4] * dv + b1.x, 0.f);
            v1.y = fmaxf(acc[5] * dv + b1.y, 0.f);
            v1.z = fmaxf(acc[6] * dv + b1.z, 0.f);
            v1.w = fmaxf(acc[7] * dv + b1.w, 0.f);
            float* op = (float*)out + (size_t)node * 64 + l8 * 8;
            *(float4*)op = v0;
            *(float4*)(op + 4) = v1;
        }
    }
}

// ---------------- launch ----------------

extern "C" void kernel_launch(void* const* d_in, const int* in_sizes, int n_in,
                              void* d_out, int out_size, void* d_ws, size_t ws_size,
                              hipStream_t stream) {
    const float* x  = (const float*)d_in[0];
    const int*   ei = (const int*)d_in[1];   // [2, E] int32
    const float* ew = (const float*)d_in[2];
    const float* W1 = (const float*)d_in[3];
    const float* b1 = (const float*)d_in[4];
    const float* W2 = (const float*)d_in[5];
    const float* b2 = (const float*)d_in[6];
    const float* W3 = (const float*)d_in[7];
    const float* b3 = (const float*)d_in[8];
    float* out = (float*)d_out;

    const int N = in_sizes[0] / K_DIM;      // 50000
    const int E = in_sizes[2];              // 800000
    const int* row = ei;                    // edge_index[0] (source)
    const int* col = ei + E;                // edge_index[1] (target / aggregation)

    const int total = E + N;                         // 850000
    const int nb = (total + SORT_ITEMS - 1) / SORT_ITEMS;   // 208
    const int ngroups = (N + 255) >> 8;              // 196 high-byte groups
    const int NW1 = 128 * 128, NW2 = 128 * 128, NW3 = 64 * 128;
    const int nwb = (NW1 + NW2 + NW3 + 255) / 256;   // 160 weight-convert blocks

    // workspace layout, 8B-aligned sections first
    u64* elA      = (u64*)d_ws;                                // total
    u64* elB      = elA + total;                               // total
    __half* m_buf = (__half*)(elB + total);                    // N*128 fp16
    __half* h_buf = m_buf + (size_t)N * K_DIM;                 // N*128 fp16
    __half* Wh    = h_buf + (size_t)N * K_DIM;                 // 40960 fp16
    u32* ghist    = (u32*)(Wh + NW1 + NW2 + NW3);              // 256*nb
    u32* dsum     = ghist + (size_t)256 * nb;                  // 256
    u32* dbase    = dsum + 256;                                // 257
    int* offs     = (int*)(dbase + 257);                       // N+1
    float* dinv   = (float*)(offs + N + 1);                    // N

    build_hist<<<nb + nwb, 256, 0, stream>>>(row, col, ew, elA, ghist, E, N, nb,
                                             W1, W2, W3, Wh, NW1, NW2, NW3);
    digit_sum<<<256, 256, 0, stream>>>(ghist, dsum, nb);
    digit_scan<<<256, 256, 0, stream>>>(ghist, dsum, dbase, nb);
    p1_scatter<<<nb, 256, 0, stream>>>(elA, ghist, elB, total, nb);

    const int gemm1_blocks = (N + 255) / 256;        // 196 (16-wave tiles)
    // merged: p2 sort (ngroups blocks) + layer-1 GEMM (gemm1_blocks blocks)
    p2_gemm<<<ngroups + gemm1_blocks, 1024, 0, stream>>>(
        elB, elA, dbase, offs, dinv, N, ngroups, x, Wh, m_buf);

    const int gemm_blocks = (N + 63) / 64;
    const int agg_blocks = (N + 3) / 4;
    const int2* csr = (const int2*)elA;

    // layer 1 agg: h = fp16(relu(dinv_n * sum (ew*dinv_s)*m_raw + b1))
    agg_kernel<128, __half><<<agg_blocks, 256, 0, stream>>>(m_buf, offs, csr, dinv, b1, h_buf, N);
    // layer 2
    mfma_gemm<128><<<gemm_blocks, 256, 0, stream>>>(h_buf, Wh + NW1, m_buf, N);
    agg_kernel<128, __half><<<agg_blocks, 256, 0, stream>>>(m_buf, offs, csr, dinv, b2, h_buf, N);
    // layer 3: F_OUT=64, write d_out (fp32) directly
    mfma_gemm<64><<<gemm_blocks, 256, 0, stream>>>(h_buf, Wh + NW1 + NW2, m_buf, N);
    agg_kernel<64, float><<<agg_blocks, 256, 0, stream>>>(m_buf, offs, csr, dinv, b3, out, N);
}

// Round 8
// 268.322 us; speedup vs baseline: 1.1482x; 1.0235x over previous
//
#include <hip/hip_runtime.h>
#include <hip/hip_fp16.h>

// GraphEmbedNet: 3-layer GCN, N=50000, E=800000, F=128/128/64.
// R21 (on R20 = 274.6us best): agg gather pipeline deepened STRUCTURALLY.
// R19/R20's dynamic loop issues 1 gather/round -> ~5 serial LLC round-trips
// per node (deg~17). Now: masked-head (nr%16) + full 16-edge iterations with
// 4 INDEPENDENT gathers in flight (D=128; D=64 uses 32-edge iters, 4 gathers).
// Unlike R17's falsified 16-deep dependent e->f chains, these 4 gathers
// depend only on the one already-loaded header (shfl) and keep just 32 VGPR
// of load data live -- the regime the compiler handles (R16 evidence).
// Masked slots: weight 0; shfl'd src ids are always valid rows, no clamp.
// Everything else R20-verbatim (merged p2+gemm1, dinv folded into agg,
// quarter-private p2@1024, LDS-staged p1, R13 digit_sum/scan).

#define K_DIM 128
#define SORT_ITEMS 4096   // elements per pass-1 block

typedef unsigned long long u64;
typedef unsigned int u32;

using half8   = __attribute__((ext_vector_type(8))) _Float16;
using floatx4 = __attribute__((ext_vector_type(4))) float;

// ---------------- sort-based CSR build ----------------

// fused: pack edges + self-loops AND per-block 256-bin hist of high byte.
// blocks [nb, nb+nwb): convert W1|W2|W3 fp32 -> fp16 instead.
__global__ void build_hist(const int* __restrict__ row, const int* __restrict__ col,
                           const float* __restrict__ ew, u64* __restrict__ el,
                           u32* __restrict__ ghist, int E, int N, int nb,
                           const float* __restrict__ W1, const float* __restrict__ W2,
                           const float* __restrict__ W3, __half* __restrict__ Wh,
                           int nw1, int nw2, int nw3) {
    const int b = blockIdx.x;
    if (b >= nb) {
        const int i = (b - nb) * 256 + threadIdx.x;
        const int tot = nw1 + nw2 + nw3;
        if (i < tot) {
            float v = (i < nw1) ? W1[i] : (i < nw1 + nw2 ? W2[i - nw1] : W3[i - nw1 - nw2]);
            Wh[i] = __float2half_rn(v);
        }
        return;
    }
    __shared__ u32 bin[256];
    bin[threadIdx.x] = 0;
    __syncthreads();
    const int total = E + N;
    const int base = b * SORT_ITEMS;
    const int end = min(base + SORT_ITEMS, total);
    for (int i = base + threadIdx.x; i < end; i += 256) {
        u64 e;
        if (i < E) {
            e = ((u64)(u32)col[i] << 48) | ((u64)(u32)row[i] << 32)
              | (u64)__float_as_uint(ew[i]);
        } else {
            int v = i - E;
            e = ((u64)(u32)v << 48) | ((u64)(u32)v << 32)
              | (u64)__float_as_uint(1.0f);
        }
        el[i] = e;
        atomicAdd(&bin[(u32)(e >> 56)], 1u);
    }
    __syncthreads();
    ghist[(size_t)threadIdx.x * nb + b] = bin[threadIdx.x];
}

// block d reduces ghist[d*nb .. d*nb+nb) -> dsum[d]   (R13 form)
__global__ void digit_sum(const u32* __restrict__ ghist, u32* __restrict__ dsum, int nb) {
    __shared__ u32 s[256];
    const int d = blockIdx.x;
    u32 acc = 0;
    for (int i = threadIdx.x; i < nb; i += 256) acc += ghist[(size_t)d * nb + i];
    s[threadIdx.x] = acc;
    __syncthreads();
    for (int off = 128; off > 0; off >>= 1) {
        if (threadIdx.x < off) s[threadIdx.x] += s[threadIdx.x + off];
        __syncthreads();
    }
    if (threadIdx.x == 0) dsum[d] = s[0];
}

// block d: re-scan dsum in LDS for its digit base, write dbase[d] (+[256]),
// then exclusive-scan its nb block-counts in place.   (R13 form)
__global__ void digit_scan(u32* __restrict__ ghist, const u32* __restrict__ dsum,
                           u32* __restrict__ dbase, int nb) {
    __shared__ u32 ds[256];
    __shared__ u32 s[256];
    const int d = blockIdx.x, t = threadIdx.x;
    ds[t] = dsum[t];
    __syncthreads();
    for (int off = 1; off < 256; off <<= 1) {
        u32 u = (t >= off) ? ds[t - off] : 0;
        __syncthreads();
        ds[t] += u;
        __syncthreads();
    }
    u32 carry = (d == 0) ? 0u : ds[d - 1];   // exclusive digit base
    if (t == 0) dbase[d] = carry;
    if (d == 255 && t == 0) dbase[256] = ds[255];
    for (int base = 0; base < nb; base += 256) {
        const int i = base + t;
        const u32 v = (i < nb) ? ghist[(size_t)d * nb + i] : 0;
        s[t] = v;
        __syncthreads();
        for (int off = 1; off < 256; off <<= 1) {
            u32 u = (t >= off) ? s[t - off] : 0;
            __syncthreads();
            s[t] += u;
            __syncthreads();
        }
        if (i < nb) ghist[(size_t)d * nb + i] = carry + s[t] - v;
        carry += s[255];
        __syncthreads();
    }
}

// pass 1 scatter, R16 form: LDS-staged coalesced flush.
__global__ __launch_bounds__(256) void p1_scatter(const u64* __restrict__ el,
                                                  const u32* __restrict__ ghist,
                                                  u64* __restrict__ out, int total, int nb) {
    __shared__ u32 gbase[256];
    __shared__ u32 lbase[256];
    __shared__ u32 lcur[256];
    __shared__ u64 buf[SORT_ITEMS];
    const int t = threadIdx.x;
    gbase[t] = ghist[(size_t)t * nb + blockIdx.x];
    lcur[t] = 0;                       // used as histogram first
    __syncthreads();
    const int base = blockIdx.x * SORT_ITEMS;
    const int end = min(base + SORT_ITEMS, total);
    const int cnt = end - base;

    u64 it[16];
    bool ok[16];
#pragma unroll
    for (int j = 0; j < 16; ++j) {
        const int i = base + t + j * 256;
        ok[j] = i < end;
        it[j] = ok[j] ? el[i] : 0;
        if (ok[j]) atomicAdd(&lcur[(u32)(it[j] >> 56)], 1u);
    }
    __syncthreads();
    const u32 v = lcur[t];
    lbase[t] = v;
    __syncthreads();
    for (int off = 1; off < 256; off <<= 1) {
        u32 u = (t >= off) ? lbase[t - off] : 0;
        __syncthreads();
        lbase[t] += u;
        __syncthreads();
    }
    const u32 excl = lbase[t] - v;     // exclusive local base for digit t
    __syncthreads();
    lbase[t] = excl;
    lcur[t] = excl;
    __syncthreads();
#pragma unroll
    for (int j = 0; j < 16; ++j) {
        if (ok[j]) {
            const u32 d = (u32)(it[j] >> 56);
            const u32 p = atomicAdd(&lcur[d], 1u);
            buf[p] = it[j];
        }
    }
    __syncthreads();
    for (int i = t; i < cnt; i += 256) {
        const u64 e = buf[i];
        const u32 d = (u32)(e >> 56);
        out[gbase[d] + i - lbase[d]] = e;
    }
}

// ---------------- merged pass 2 + layer-1 GEMM ----------------
// blocks [0, ngroups): quarter-private counting sort (1024 thr).
// blocks [ngroups, ...): 16-wave MFMA GEMM m_raw = fp16(x @ W1^T).
__global__ __launch_bounds__(1024) void p2_gemm(
        const u64* __restrict__ in, u64* __restrict__ out,
        const u32* __restrict__ dbase,
        int* __restrict__ offs, float* __restrict__ dinv, int n, int ngroups,
        const float* __restrict__ x, const __half* __restrict__ Wh,
        __half* __restrict__ C) {
    if ((int)blockIdx.x < ngroups) {
        // ---- p2 quarter-private sort ----
        const int t = threadIdx.x;
        const int q = t >> 8;          // quarter 0..3
        const int b = t & 255;
        const int base = (int)dbase[blockIdx.x];
        const int size = (int)dbase[blockIdx.x + 1] - base;
        __shared__ u32 hist[4][256];
        __shared__ u32 cur[4][256];
        __shared__ u32 s[256];
        __shared__ float wsum[4][256];
        hist[q][b] = 0;
        wsum[q][b] = 0.f;
        __syncthreads();
        for (int i = t; i < size; i += 1024)
            atomicAdd(&hist[q][(u32)(in[base + i] >> 48) & 0xFFu], 1u);
        __syncthreads();
        u32 v = 0;
        if (t < 256) {
            v = hist[0][b] + hist[1][b] + hist[2][b] + hist[3][b];
            s[b] = v;
        }
        __syncthreads();
        for (int off = 1; off < 256; off <<= 1) {
            u32 u = (t < 256 && b >= off) ? s[b - off] : 0;
            __syncthreads();
            if (t < 256) s[b] += u;
            __syncthreads();
        }
        u32 mystart = 0;
        if (t < 256) {
            mystart = (u32)base + s[b] - v;   // node (blockIdx*256+b)'s run start
            u32 c = mystart;
            cur[0][b] = c; c += hist[0][b];
            cur[1][b] = c; c += hist[1][b];
            cur[2][b] = c; c += hist[2][b];
            cur[3][b] = c;
        }
        __syncthreads();
        for (int i = t; i < size; i += 1024) {
            u64 e = in[base + i];
            u32 lo = (u32)(e >> 48) & 0xFFu;
            u32 p = atomicAdd(&cur[q][lo], 1u);
            out[p] = e;
            atomicAdd(&wsum[q][lo], __uint_as_float((u32)(e & 0xFFFFFFFFu)));
        }
        __syncthreads();
        const int node = blockIdx.x * 256 + b;
        if (t < 256 && node < n && v > 0) {
            offs[node] = (int)mystart;
            dinv[node] = rsqrtf(wsum[0][b] + wsum[1][b] + wsum[2][b] + wsum[3][b]);
            if (node == n - 1) offs[n] = (int)(mystart + v);
        }
    } else {
        // ---- layer-1 GEMM tile: 16 waves x 16 rows, BN=128, fp32 input ----
        const int gb = blockIdx.x - ngroups;
        const int wave = threadIdx.x >> 6;
        const int lane = threadIdx.x & 63;
        const int quad = lane >> 4;
        const int l16  = lane & 15;
        const int row0 = gb * 256 + wave * 16;

        int arow = row0 + l16;
        if (arow > n - 1) arow = n - 1;

        floatx4 acc[8] = {};
#pragma unroll
        for (int kc = 0; kc < 4; ++kc) {
            const int kof = kc * 32 + quad * 8;
            const float* ap = x + (size_t)arow * K_DIM + kof;
            float4 f0 = *(const float4*)ap;
            float4 f1 = *(const float4*)(ap + 4);
            half8 af;
            af[0] = (_Float16)f0.x; af[1] = (_Float16)f0.y;
            af[2] = (_Float16)f0.z; af[3] = (_Float16)f0.w;
            af[4] = (_Float16)f1.x; af[5] = (_Float16)f1.y;
            af[6] = (_Float16)f1.z; af[7] = (_Float16)f1.w;
#pragma unroll
            for (int ct = 0; ct < 8; ++ct) {
                half8 bf = *(const half8*)(Wh + (size_t)(ct * 16 + l16) * K_DIM + kof);
                acc[ct] = __builtin_amdgcn_mfma_f32_16x16x32_f16(af, bf, acc[ct], 0, 0, 0);
            }
        }
        int grow[4];
        bool ok[4];
#pragma unroll
        for (int r = 0; r < 4; ++r) {
            grow[r] = row0 + quad * 4 + r;
            ok[r] = grow[r] < n;
        }
#pragma unroll
        for (int ct = 0; ct < 8; ++ct) {
            const int colb = ct * 16 + l16;
#pragma unroll
            for (int r = 0; r < 4; ++r)
                if (ok[r])
                    C[(size_t)grow[r] * 128 + colb] = __float2half_rn(acc[ct][r]);
        }
    }
}

// ---------------- MFMA GEMM (layers 2,3): C[n][o] = half(sum_k A[n][k]*W[o][k]) ----------------

template <int BN>
__global__ __launch_bounds__(256) void mfma_gemm(const __half* __restrict__ Ain,
                                                 const __half* __restrict__ Wh,
                                                 __half* __restrict__ C, int nrows) {
    constexpr int NT = BN / 16;
    const int wave = threadIdx.x >> 6;
    const int lane = threadIdx.x & 63;
    const int quad = lane >> 4;
    const int l16  = lane & 15;
    const int row0 = blockIdx.x * 64 + wave * 16;

    int arow = row0 + l16;
    if (arow > nrows - 1) arow = nrows - 1;

    floatx4 acc[NT] = {};

#pragma unroll
    for (int kc = 0; kc < 4; ++kc) {
        const int kof = kc * 32 + quad * 8;
        half8 af = *(const half8*)(Ain + (size_t)arow * K_DIM + kof);
#pragma unroll
        for (int ct = 0; ct < NT; ++ct) {
            half8 bf = *(const half8*)(Wh + (size_t)(ct * 16 + l16) * K_DIM + kof);
            acc[ct] = __builtin_amdgcn_mfma_f32_16x16x32_f16(af, bf, acc[ct], 0, 0, 0);
        }
    }

    int grow[4];
    bool ok[4];
#pragma unroll
    for (int r = 0; r < 4; ++r) {
        grow[r] = row0 + quad * 4 + r;
        ok[r] = grow[r] < nrows;
    }
#pragma unroll
    for (int ct = 0; ct < NT; ++ct) {
        const int colb = ct * 16 + l16;
#pragma unroll
        for (int r = 0; r < 4; ++r)
            if (ok[r])
                C[(size_t)grow[r] * BN + colb] = __float2half_rn(acc[ct][r]);
    }
}

// ---------------- aggregation ----------------
// out[i] = relu(bias + dinv[i] * sum_e (ew_e * dinv[src_e]) * m_raw[src_e])
// R21: masked-head + unrolled body with 4 independent gathers in flight.
// D=128: quads = 4 edges/gather-instr, 16 edges/iteration.
// D=64:  octs  = 8 edges/gather-instr, 32 edges/iteration.

template <int D, typename OUT>
__global__ __launch_bounds__(256) void agg_kernel(
    const __half* __restrict__ m, const int* __restrict__ offs,
    const int2* __restrict__ csr, const float* __restrict__ dinv,
    const float* __restrict__ bias, OUT* __restrict__ out, int n) {
    const int wid = threadIdx.x >> 6;
    const int lane = threadIdx.x & 63;
    const int node = (blockIdx.x << 2) + wid;
    if (node >= n) return;
    const int beg = offs[node];
    const int end = offs[node + 1];
    const int cnt = end - beg;          // >= 1 (self-loop)
    const half8* mrow = (const half8*)m;

    // one coalesced load fetches up to 64 csr entries for this node
    const int2 ev = csr[beg + min(lane, cnt - 1)];
    const int   sv = ev.y & 0xFFFF;
    const float ds = dinv[sv];                      // L2-hot (200KB table)
    const float wv = (lane < cnt) ? __int_as_float(ev.x) * ds : 0.f;
    const int nr = min(cnt, 64);

    float acc[8] = {0.f, 0.f, 0.f, 0.f, 0.f, 0.f, 0.f, 0.f};

    if constexpr (D == 128) {
        const int quad = lane >> 4;
        const int l16  = lane & 15;
        const int rem = nr & 15;
        if (rem) {
            // masked head: edges [0, rem) via slots {quad, 4+quad, 8+quad, 12+quad}
            float w0 = __shfl(wv, quad),      w1 = __shfl(wv, 4 + quad);
            float w2 = __shfl(wv, 8 + quad),  w3 = __shfl(wv, 12 + quad);
            int   s0 = __shfl(sv, quad),      s1 = __shfl(sv, 4 + quad);
            int   s2 = __shfl(sv, 8 + quad),  s3 = __shfl(sv, 12 + quad);
            w0 = (quad      < rem) ? w0 : 0.f;
            w1 = (4 + quad  < rem) ? w1 : 0.f;
            w2 = (8 + quad  < rem) ? w2 : 0.f;
            w3 = (12 + quad < rem) ? w3 : 0.f;
            half8 h0 = mrow[(size_t)s0 * 16 + l16];
            half8 h1 = mrow[(size_t)s1 * 16 + l16];
            half8 h2 = mrow[(size_t)s2 * 16 + l16];
            half8 h3 = mrow[(size_t)s3 * 16 + l16];
#pragma unroll
            for (int i = 0; i < 8; ++i) {
                acc[i] = fmaf(w0, (float)h0[i], acc[i]);
                acc[i] = fmaf(w1, (float)h1[i], acc[i]);
                acc[i] = fmaf(w2, (float)h2[i], acc[i]);
                acc[i] = fmaf(w3, (float)h3[i], acc[i]);
            }
        }
        for (int k = rem; k < nr; k += 16) {
            float w0 = __shfl(wv, k + quad),      w1 = __shfl(wv, k + 4 + quad);
            float w2 = __shfl(wv, k + 8 + quad),  w3 = __shfl(wv, k + 12 + quad);
            int   s0 = __shfl(sv, k + quad),      s1 = __shfl(sv, k + 4 + quad);
            int   s2 = __shfl(sv, k + 8 + quad),  s3 = __shfl(sv, k + 12 + quad);
            half8 h0 = mrow[(size_t)s0 * 16 + l16];
            half8 h1 = mrow[(size_t)s1 * 16 + l16];
            half8 h2 = mrow[(size_t)s2 * 16 + l16];
            half8 h3 = mrow[(size_t)s3 * 16 + l16];
#pragma unroll
            for (int i = 0; i < 8; ++i) {
                acc[i] = fmaf(w0, (float)h0[i], acc[i]);
                acc[i] = fmaf(w1, (float)h1[i], acc[i]);
                acc[i] = fmaf(w2, (float)h2[i], acc[i]);
                acc[i] = fmaf(w3, (float)h3[i], acc[i]);
            }
        }
        // rare: degree > 64 tail, per-quad strided
        for (int k = beg + 64 + quad; k < end; k += 4) {
            const int2 e0 = csr[k];
            const int  s0 = e0.y & 0xFFFF;
            const float w0 = __int_as_float(e0.x) * dinv[s0];
            half8 hv = mrow[(size_t)s0 * 16 + l16];
#pragma unroll
            for (int i = 0; i < 8; ++i)
                acc[i] = fmaf(w0, (float)hv[i], acc[i]);
        }
#pragma unroll
        for (int i = 0; i < 8; ++i) {
            acc[i] += __shfl_xor(acc[i], 16);
            acc[i] += __shfl_xor(acc[i], 32);
        }
        if (quad == 0) {
            const float dv = dinv[node];
            const float4 b0 = *(const float4*)(bias + l16 * 8);
            const float4 b1 = *(const float4*)(bias + l16 * 8 + 4);
            const float bb[8] = {b0.x, b0.y, b0.z, b0.w, b1.x, b1.y, b1.z, b1.w};
            half8 ho;
#pragma unroll
            for (int i = 0; i < 8; ++i)
                ho[i] = (_Float16)fmaxf(acc[i] * dv + bb[i], 0.f);
            *(half8*)((__half*)out + (size_t)node * 128 + l16 * 8) = ho;
        }
    } else {
        // D == 64
        const int oct = lane >> 3;
        const int l8  = lane & 7;
        const int rem = nr & 31;
        if (rem) {
            // masked head: edges [0, rem) via slots {oct, 8+oct, 16+oct, 24+oct}
            float w0 = __shfl(wv, oct),       w1 = __shfl(wv, 8 + oct);
            float w2 = __shfl(wv, 16 + oct),  w3 = __shfl(wv, 24 + oct);
            int   s0 = __shfl(sv, oct),       s1 = __shfl(sv, 8 + oct);
            int   s2 = __shfl(sv, 16 + oct),  s3 = __shfl(sv, 24 + oct);
            w0 = (oct      < rem) ? w0 : 0.f;
            w1 = (8 + oct  < rem) ? w1 : 0.f;
            w2 = (16 + oct < rem) ? w2 : 0.f;
            w3 = (24 + oct < rem) ? w3 : 0.f;
            half8 h0 = mrow[(size_t)s0 * 8 + l8];
            half8 h1 = mrow[(size_t)s1 * 8 + l8];
            half8 h2 = mrow[(size_t)s2 * 8 + l8];
            half8 h3 = mrow[(size_t)s3 * 8 + l8];
#pragma unroll
            for (int i = 0; i < 8; ++i) {
                acc[i] = fmaf(w0, (float)h0[i], acc[i]);
                acc[i] = fmaf(w1, (float)h1[i], acc[i]);
                acc[i] = fmaf(w2, (float)h2[i], acc[i]);
                acc[i] = fmaf(w3, (float)h3[i], acc[i]);
            }
        }
        for (int k = rem; k < nr; k += 32) {
            float w0 = __shfl(wv, k + oct),       w1 = __shfl(wv, k + 8 + oct);
            float w2 = __shfl(wv, k + 16 + oct),  w3 = __shfl(wv, k + 24 + oct);
            int   s0 = __shfl(sv, k + oct),       s1 = __shfl(sv, k + 8 + oct);
            int   s2 = __shfl(sv, k + 16 + oct),  s3 = __shfl(sv, k + 24 + oct);
            half8 h0 = mrow[(size_t)s0 * 8 + l8];
            half8 h1 = mrow[(size_t)s1 * 8 + l8];
            half8 h2 = mrow[(size_t)s2 * 8 + l8];
            half8 h3 = mrow[(size_t)s3 * 8 + l8];
#pragma unroll
            for (int i = 0; i < 8; ++i) {
                acc[i] = fmaf(w0, (float)h0[i], acc[i]);
                acc[i] = fmaf(w1, (float)h1[i], acc[i]);
                acc[i] = fmaf(w2, (float)h2[i], acc[i]);
                acc[i] = fmaf(w3, (float)h3[i], acc[i]);
            }
        }
        for (int k = beg + 64 + oct; k < end; k += 8) {
            const int2 e0 = csr[k];
            const int  s0 = e0.y & 0xFFFF;
            const float w0 = __int_as_float(e0.x) * dinv[s0];
            half8 hv = mrow[(size_t)s0 * 8 + l8];
#pragma unroll
            for (int i = 0; i < 8; ++i)
                acc[i] = fmaf(w0, (float)hv[i], acc[i]);
        }
#pragma unroll
        for (int i = 0; i < 8; ++i) {
            acc[i] += __shfl_xor(acc[i], 8);
            acc[i] += __shfl_xor(acc[i], 16);
            acc[i] += __shfl_xor(acc[i], 32);
        }
        if (oct == 0) {
            const float dv = dinv[node];
            const float4 b0 = *(const float4*)(bias + l8 * 8);
            const float4 b1 = *(const float4*)(bias + l8 * 8 + 4);
            float4 v0, v1;
            v0.x = fmaxf(acc[0] * dv + b0.x, 0.f);
            v0.y = fmaxf(acc[1] * dv + b0.y, 0.f);
            v0.z = fmaxf(acc[2] * dv + b0.z, 0.f);
            v0.w = fmaxf(acc[3] * dv + b0.w, 0.f);
            v1.x = fmaxf(acc[4] * dv + b1.x, 0.f);
            v1.y = fmaxf(acc[5] * dv + b1.y, 0.f);
            v1.z = fmaxf(acc[6] * dv + b1.z, 0.f);
            v1.w = fmaxf(acc[7] * dv + b1.w, 0.f);
            float* op = (float*)out + (size_t)node * 64 + l8 * 8;
            *(float4*)op = v0;
            *(float4*)(op + 4) = v1;
        }
    }
}

// ---------------- launch ----------------

extern "C" void kernel_launch(void* const* d_in, const int* in_sizes, int n_in,
                              void* d_out, int out_size, void* d_ws, size_t ws_size,
                              hipStream_t stream) {
    const float* x  = (const float*)d_in[0];
    const int*   ei = (const int*)d_in[1];   // [2, E] int32
    const float* ew = (const float*)d_in[2];
    const float* W1 = (const float*)d_in[3];
    const float* b1 = (const float*)d_in[4];
    const float* W2 = (const float*)d_in[5];
    const float* b2 = (const float*)d_in[6];
    const float* W3 = (const float*)d_in[7];
    const float* b3 = (const float*)d_in[8];
    float* out = (float*)d_out;

    const int N = in_sizes[0] / K_DIM;      // 50000
    const int E = in_sizes[2];              // 800000
    const int* row = ei;                    // edge_index[0] (source)
    const int* col = ei + E;                // edge_index[1] (target / aggregation)

    const int total = E + N;                         // 850000
    const int nb = (total + SORT_ITEMS - 1) / SORT_ITEMS;   // 208
    const int ngroups = (N + 255) >> 8;              // 196 high-byte groups
    const int NW1 = 128 * 128, NW2 = 128 * 128, NW3 = 64 * 128;
    const int nwb = (NW1 + NW2 + NW3 + 255) / 256;   // 160 weight-convert blocks

    // workspace layout, 8B-aligned sections first
    u64* elA      = (u64*)d_ws;                                // total
    u64* elB      = elA + total;                               // total
    __half* m_buf = (__half*)(elB + total);                    // N*128 fp16
    __half* h_buf = m_buf + (size_t)N * K_DIM;                 // N*128 fp16
    __half* Wh    = h_buf + (size_t)N * K_DIM;                 // 40960 fp16
    u32* ghist    = (u32*)(Wh + NW1 + NW2 + NW3);              // 256*nb
    u32* dsum     = ghist + (size_t)256 * nb;                  // 256
    u32* dbase    = dsum + 256;                                // 257
    int* offs     = (int*)(dbase + 257);                       // N+1
    float* dinv   = (float*)(offs + N + 1);                    // N

    build_hist<<<nb + nwb, 256, 0, stream>>>(row, col, ew, elA, ghist, E, N, nb,
                                             W1, W2, W3, Wh, NW1, NW2, NW3);
    digit_sum<<<256, 256, 0, stream>>>(ghist, dsum, nb);
    digit_scan<<<256, 256, 0, stream>>>(ghist, dsum, dbase, nb);
    p1_scatter<<<nb, 256, 0, stream>>>(elA, ghist, elB, total, nb);

    const int gemm1_blocks = (N + 255) / 256;        // 196 (16-wave tiles)
    // merged: p2 sort (ngroups blocks) + layer-1 GEMM (gemm1_blocks blocks)
    p2_gemm<<<ngroups + gemm1_blocks, 1024, 0, stream>>>(
        elB, elA, dbase, offs, dinv, N, ngroups, x, Wh, m_buf);

    const int gemm_blocks = (N + 63) / 64;
    const int agg_blocks = (N + 3) / 4;
    const int2* csr = (const int2*)elA;

    // layer 1 agg: h = fp16(relu(dinv_n * sum (ew*dinv_s)*m_raw + b1))
    agg_kernel<128, __half><<<agg_blocks, 256, 0, stream>>>(m_buf, offs, csr, dinv, b1, h_buf, N);
    // layer 2
    mfma_gemm<128><<<gemm_blocks, 256, 0, stream>>>(h_buf, Wh + NW1, m_buf, N);
    agg_kernel<128, __half><<<agg_blocks, 256, 0, stream>>>(m_buf, offs, csr, dinv, b2, h_buf, N);
    // layer 3: F_OUT=64, write d_out (fp32) directly
    mfma_gemm<64><<<gemm_blocks, 256, 0, stream>>>(h_buf, Wh + NW1 + NW2, m_buf, N);
    agg_kernel<64, float><<<agg_blocks, 256, 0, stream>>>(m_buf, offs, csr, dinv, b3, out, N);
}

// Round 9
// 266.406 us; speedup vs baseline: 1.1565x; 1.0072x over previous
//
#include <hip/hip_runtime.h>
#include <hip/hip_fp16.h>

// GraphEmbedNet: 3-layer GCN, N=50000, E=800000, F=128/128/64.
// R22 (on R21 = 268.3us best): split layer-1 GEMM across BOTH sort-phase
// launches. R20 proved p2||gemm1 overlap; but p1_scatter (208 blocks, ~7us,
// latency-bound, 48+ idle CUs) overlapped nothing while p2 carried ALL of
// gemm1 (~15-18us). Now: p1 launch gets a 392-block tail of 64-row/4-wave
// gemm tiles (rows 0..25088; Wh ready since build_hist), p2 keeps 98
// 16-wave tiles (rows 25088..50000). Phase sum max(p1,g1)+max(p2,g2) ~19us
// vs 7+21 ~28us. Sort blocks sit at grid front -> dispatch first.
// NOTE: p1 kernel's 33KB static LDS applies to its gemm blocks too (4
// blocks/CU cap) -- acceptable for a BW-bound tile.
// Everything else R21-verbatim (4-wide agg volleys, dinv folded into agg,
// quarter-private p2@1024, LDS-staged p1, R13 digit_sum/scan).

#define K_DIM 128
#define SORT_ITEMS 4096   // elements per pass-1 block

typedef unsigned long long u64;
typedef unsigned int u32;

using half8   = __attribute__((ext_vector_type(8))) _Float16;
using floatx4 = __attribute__((ext_vector_type(4))) float;

// ---------------- sort-based CSR build ----------------

// fused: pack edges + self-loops AND per-block 256-bin hist of high byte.
// blocks [nb, nb+nwb): convert W1|W2|W3 fp32 -> fp16 instead.
__global__ void build_hist(const int* __restrict__ row, const int* __restrict__ col,
                           const float* __restrict__ ew, u64* __restrict__ el,
                           u32* __restrict__ ghist, int E, int N, int nb,
                           const float* __restrict__ W1, const float* __restrict__ W2,
                           const float* __restrict__ W3, __half* __restrict__ Wh,
                           int nw1, int nw2, int nw3) {
    const int b = blockIdx.x;
    if (b >= nb) {
        const int i = (b - nb) * 256 + threadIdx.x;
        const int tot = nw1 + nw2 + nw3;
        if (i < tot) {
            float v = (i < nw1) ? W1[i] : (i < nw1 + nw2 ? W2[i - nw1] : W3[i - nw1 - nw2]);
            Wh[i] = __float2half_rn(v);
        }
        return;
    }
    __shared__ u32 bin[256];
    bin[threadIdx.x] = 0;
    __syncthreads();
    const int total = E + N;
    const int base = b * SORT_ITEMS;
    const int end = min(base + SORT_ITEMS, total);
    for (int i = base + threadIdx.x; i < end; i += 256) {
        u64 e;
        if (i < E) {
            e = ((u64)(u32)col[i] << 48) | ((u64)(u32)row[i] << 32)
              | (u64)__float_as_uint(ew[i]);
        } else {
            int v = i - E;
            e = ((u64)(u32)v << 48) | ((u64)(u32)v << 32)
              | (u64)__float_as_uint(1.0f);
        }
        el[i] = e;
        atomicAdd(&bin[(u32)(e >> 56)], 1u);
    }
    __syncthreads();
    ghist[(size_t)threadIdx.x * nb + b] = bin[threadIdx.x];
}

// block d reduces ghist[d*nb .. d*nb+nb) -> dsum[d]   (R13 form)
__global__ void digit_sum(const u32* __restrict__ ghist, u32* __restrict__ dsum, int nb) {
    __shared__ u32 s[256];
    const int d = blockIdx.x;
    u32 acc = 0;
    for (int i = threadIdx.x; i < nb; i += 256) acc += ghist[(size_t)d * nb + i];
    s[threadIdx.x] = acc;
    __syncthreads();
    for (int off = 128; off > 0; off >>= 1) {
        if (threadIdx.x < off) s[threadIdx.x] += s[threadIdx.x + off];
        __syncthreads();
    }
    if (threadIdx.x == 0) dsum[d] = s[0];
}

// block d: re-scan dsum in LDS for its digit base, write dbase[d] (+[256]),
// then exclusive-scan its nb block-counts in place.   (R13 form)
__global__ void digit_scan(u32* __restrict__ ghist, const u32* __restrict__ dsum,
                           u32* __restrict__ dbase, int nb) {
    __shared__ u32 ds[256];
    __shared__ u32 s[256];
    const int d = blockIdx.x, t = threadIdx.x;
    ds[t] = dsum[t];
    __syncthreads();
    for (int off = 1; off < 256; off <<= 1) {
        u32 u = (t >= off) ? ds[t - off] : 0;
        __syncthreads();
        ds[t] += u;
        __syncthreads();
    }
    u32 carry = (d == 0) ? 0u : ds[d - 1];   // exclusive digit base
    if (t == 0) dbase[d] = carry;
    if (d == 255 && t == 0) dbase[256] = ds[255];
    for (int base = 0; base < nb; base += 256) {
        const int i = base + t;
        const u32 v = (i < nb) ? ghist[(size_t)d * nb + i] : 0;
        s[t] = v;
        __syncthreads();
        for (int off = 1; off < 256; off <<= 1) {
            u32 u = (t >= off) ? s[t - off] : 0;
            __syncthreads();
            s[t] += u;
            __syncthreads();
        }
        if (i < nb) ghist[(size_t)d * nb + i] = carry + s[t] - v;
        carry += s[255];
        __syncthreads();
    }
}

// ---------------- merged pass-1 scatter + gemm1 front half ----------------
// blocks [0, nb): LDS-staged coalesced scatter (R16 form).
// blocks [nb, nb+g1): 4-wave 64-row MFMA tile, m_raw = fp16(x @ W1^T),
//   rows (b-nb)*64 .. +64. Wh ready (build_hist completed 2 launches ago).
__global__ __launch_bounds__(256) void p1_gemm(const u64* __restrict__ el,
                                               const u32* __restrict__ ghist,
                                               u64* __restrict__ out, int total, int nb,
                                               const float* __restrict__ x,
                                               const __half* __restrict__ Wh,
                                               __half* __restrict__ C, int n) {
    __shared__ u32 gbase[256];
    __shared__ u32 lbase[256];
    __shared__ u32 lcur[256];
    __shared__ u64 buf[SORT_ITEMS];
    if ((int)blockIdx.x >= nb) {
        // ---- gemm tile: 4 waves x 16 rows, BN=128, fp32 input ----
        const int gb = blockIdx.x - nb;
        const int wave = threadIdx.x >> 6;
        const int lane = threadIdx.x & 63;
        const int quad = lane >> 4;
        const int l16  = lane & 15;
        const int row0 = gb * 64 + wave * 16;

        int arow = row0 + l16;
        if (arow > n - 1) arow = n - 1;

        floatx4 acc[8] = {};
#pragma unroll
        for (int kc = 0; kc < 4; ++kc) {
            const int kof = kc * 32 + quad * 8;
            const float* ap = x + (size_t)arow * K_DIM + kof;
            float4 f0 = *(const float4*)ap;
            float4 f1 = *(const float4*)(ap + 4);
            half8 af;
            af[0] = (_Float16)f0.x; af[1] = (_Float16)f0.y;
            af[2] = (_Float16)f0.z; af[3] = (_Float16)f0.w;
            af[4] = (_Float16)f1.x; af[5] = (_Float16)f1.y;
            af[6] = (_Float16)f1.z; af[7] = (_Float16)f1.w;
#pragma unroll
            for (int ct = 0; ct < 8; ++ct) {
                half8 bf = *(const half8*)(Wh + (size_t)(ct * 16 + l16) * K_DIM + kof);
                acc[ct] = __builtin_amdgcn_mfma_f32_16x16x32_f16(af, bf, acc[ct], 0, 0, 0);
            }
        }
        int grow[4];
        bool okr[4];
#pragma unroll
        for (int r = 0; r < 4; ++r) {
            grow[r] = row0 + quad * 4 + r;
            okr[r] = grow[r] < n;
        }
#pragma unroll
        for (int ct = 0; ct < 8; ++ct) {
            const int colb = ct * 16 + l16;
#pragma unroll
            for (int r = 0; r < 4; ++r)
                if (okr[r])
                    C[(size_t)grow[r] * 128 + colb] = __float2half_rn(acc[ct][r]);
        }
        return;
    }
    const int t = threadIdx.x;
    gbase[t] = ghist[(size_t)t * nb + blockIdx.x];
    lcur[t] = 0;                       // used as histogram first
    __syncthreads();
    const int base = blockIdx.x * SORT_ITEMS;
    const int end = min(base + SORT_ITEMS, total);
    const int cnt = end - base;

    u64 it[16];
    bool ok[16];
#pragma unroll
    for (int j = 0; j < 16; ++j) {
        const int i = base + t + j * 256;
        ok[j] = i < end;
        it[j] = ok[j] ? el[i] : 0;
        if (ok[j]) atomicAdd(&lcur[(u32)(it[j] >> 56)], 1u);
    }
    __syncthreads();
    const u32 v = lcur[t];
    lbase[t] = v;
    __syncthreads();
    for (int off = 1; off < 256; off <<= 1) {
        u32 u = (t >= off) ? lbase[t - off] : 0;
        __syncthreads();
        lbase[t] += u;
        __syncthreads();
    }
    const u32 excl = lbase[t] - v;     // exclusive local base for digit t
    __syncthreads();
    lbase[t] = excl;
    lcur[t] = excl;
    __syncthreads();
#pragma unroll
    for (int j = 0; j < 16; ++j) {
        if (ok[j]) {
            const u32 d = (u32)(it[j] >> 56);
            const u32 p = atomicAdd(&lcur[d], 1u);
            buf[p] = it[j];
        }
    }
    __syncthreads();
    for (int i = t; i < cnt; i += 256) {
        const u64 e = buf[i];
        const u32 d = (u32)(e >> 56);
        out[gbase[d] + i - lbase[d]] = e;
    }
}

// ---------------- merged pass 2 + gemm1 back half ----------------
// blocks [0, ngroups): quarter-private counting sort (1024 thr).
// blocks [ngroups, ...): 16-wave MFMA tiles, rows rowoff + gb*256.
__global__ __launch_bounds__(1024) void p2_gemm(
        const u64* __restrict__ in, u64* __restrict__ out,
        const u32* __restrict__ dbase,
        int* __restrict__ offs, float* __restrict__ dinv, int n, int ngroups,
        const float* __restrict__ x, const __half* __restrict__ Wh,
        __half* __restrict__ C, int rowoff) {
    if ((int)blockIdx.x < ngroups) {
        // ---- p2 quarter-private sort ----
        const int t = threadIdx.x;
        const int q = t >> 8;          // quarter 0..3
        const int b = t & 255;
        const int base = (int)dbase[blockIdx.x];
        const int size = (int)dbase[blockIdx.x + 1] - base;
        __shared__ u32 hist[4][256];
        __shared__ u32 cur[4][256];
        __shared__ u32 s[256];
        __shared__ float wsum[4][256];
        hist[q][b] = 0;
        wsum[q][b] = 0.f;
        __syncthreads();
        for (int i = t; i < size; i += 1024)
            atomicAdd(&hist[q][(u32)(in[base + i] >> 48) & 0xFFu], 1u);
        __syncthreads();
        u32 v = 0;
        if (t < 256) {
            v = hist[0][b] + hist[1][b] + hist[2][b] + hist[3][b];
            s[b] = v;
        }
        __syncthreads();
        for (int off = 1; off < 256; off <<= 1) {
            u32 u = (t < 256 && b >= off) ? s[b - off] : 0;
            __syncthreads();
            if (t < 256) s[b] += u;
            __syncthreads();
        }
        u32 mystart = 0;
        if (t < 256) {
            mystart = (u32)base + s[b] - v;   // node (blockIdx*256+b)'s run start
            u32 c = mystart;
            cur[0][b] = c; c += hist[0][b];
            cur[1][b] = c; c += hist[1][b];
            cur[2][b] = c; c += hist[2][b];
            cur[3][b] = c;
        }
        __syncthreads();
        for (int i = t; i < size; i += 1024) {
            u64 e = in[base + i];
            u32 lo = (u32)(e >> 48) & 0xFFu;
            u32 p = atomicAdd(&cur[q][lo], 1u);
            out[p] = e;
            atomicAdd(&wsum[q][lo], __uint_as_float((u32)(e & 0xFFFFFFFFu)));
        }
        __syncthreads();
        const int node = blockIdx.x * 256 + b;
        if (t < 256 && node < n && v > 0) {
            offs[node] = (int)mystart;
            dinv[node] = rsqrtf(wsum[0][b] + wsum[1][b] + wsum[2][b] + wsum[3][b]);
            if (node == n - 1) offs[n] = (int)(mystart + v);
        }
    } else {
        // ---- gemm tile: 16 waves x 16 rows, BN=128, fp32 input ----
        const int gb = blockIdx.x - ngroups;
        const int wave = threadIdx.x >> 6;
        const int lane = threadIdx.x & 63;
        const int quad = lane >> 4;
        const int l16  = lane & 15;
        const int row0 = rowoff + gb * 256 + wave * 16;

        int arow = row0 + l16;
        if (arow > n - 1) arow = n - 1;

        floatx4 acc[8] = {};
#pragma unroll
        for (int kc = 0; kc < 4; ++kc) {
            const int kof = kc * 32 + quad * 8;
            const float* ap = x + (size_t)arow * K_DIM + kof;
            float4 f0 = *(const float4*)ap;
            float4 f1 = *(const float4*)(ap + 4);
            half8 af;
            af[0] = (_Float16)f0.x; af[1] = (_Float16)f0.y;
            af[2] = (_Float16)f0.z; af[3] = (_Float16)f0.w;
            af[4] = (_Float16)f1.x; af[5] = (_Float16)f1.y;
            af[6] = (_Float16)f1.z; af[7] = (_Float16)f1.w;
#pragma unroll
            for (int ct = 0; ct < 8; ++ct) {
                half8 bf = *(const half8*)(Wh + (size_t)(ct * 16 + l16) * K_DIM + kof);
                acc[ct] = __builtin_amdgcn_mfma_f32_16x16x32_f16(af, bf, acc[ct], 0, 0, 0);
            }
        }
        int grow[4];
        bool ok[4];
#pragma unroll
        for (int r = 0; r < 4; ++r) {
            grow[r] = row0 + quad * 4 + r;
            ok[r] = grow[r] < n;
        }
#pragma unroll
        for (int ct = 0; ct < 8; ++ct) {
            const int colb = ct * 16 + l16;
#pragma unroll
            for (int r = 0; r < 4; ++r)
                if (ok[r])
                    C[(size_t)grow[r] * 128 + colb] = __float2half_rn(acc[ct][r]);
        }
    }
}

// ---------------- MFMA GEMM (layers 2,3): C[n][o] = half(sum_k A[n][k]*W[o][k]) ----------------

template <int BN>
__global__ __launch_bounds__(256) void mfma_gemm(const __half* __restrict__ Ain,
                                                 const __half* __restrict__ Wh,
                                                 __half* __restrict__ C, int nrows) {
    constexpr int NT = BN / 16;
    const int wave = threadIdx.x >> 6;
    const int lane = threadIdx.x & 63;
    const int quad = lane >> 4;
    const int l16  = lane & 15;
    const int row0 = blockIdx.x * 64 + wave * 16;

    int arow = row0 + l16;
    if (arow > nrows - 1) arow = nrows - 1;

    floatx4 acc[NT] = {};

#pragma unroll
    for (int kc = 0; kc < 4; ++kc) {
        const int kof = kc * 32 + quad * 8;
        half8 af = *(const half8*)(Ain + (size_t)arow * K_DIM + kof);
#pragma unroll
        for (int ct = 0; ct < NT; ++ct) {
            half8 bf = *(const half8*)(Wh + (size_t)(ct * 16 + l16) * K_DIM + kof);
            acc[ct] = __builtin_amdgcn_mfma_f32_16x16x32_f16(af, bf, acc[ct], 0, 0, 0);
        }
    }

    int grow[4];
    bool ok[4];
#pragma unroll
    for (int r = 0; r < 4; ++r) {
        grow[r] = row0 + quad * 4 + r;
        ok[r] = grow[r] < nrows;
    }
#pragma unroll
    for (int ct = 0; ct < NT; ++ct) {
        const int colb = ct * 16 + l16;
#pragma unroll
        for (int r = 0; r < 4; ++r)
            if (ok[r])
                C[(size_t)grow[r] * BN + colb] = __float2half_rn(acc[ct][r]);
    }
}

// ---------------- aggregation ----------------
// out[i] = relu(bias + dinv[i] * sum_e (ew_e * dinv[src_e]) * m_raw[src_e])
// R21 form: masked-head + unrolled body with 4 independent gathers in flight.

template <int D, typename OUT>
__global__ __launch_bounds__(256) void agg_kernel(
    const __half* __restrict__ m, const int* __restrict__ offs,
    const int2* __restrict__ csr, const float* __restrict__ dinv,
    const float* __restrict__ bias, OUT* __restrict__ out, int n) {
    const int wid = threadIdx.x >> 6;
    const int lane = threadIdx.x & 63;
    const int node = (blockIdx.x << 2) + wid;
    if (node >= n) return;
    const int beg = offs[node];
    const int end = offs[node + 1];
    const int cnt = end - beg;          // >= 1 (self-loop)
    const half8* mrow = (const half8*)m;

    // one coalesced load fetches up to 64 csr entries for this node
    const int2 ev = csr[beg + min(lane, cnt - 1)];
    const int   sv = ev.y & 0xFFFF;
    const float ds = dinv[sv];                      // L2-hot (200KB table)
    const float wv = (lane < cnt) ? __int_as_float(ev.x) * ds : 0.f;
    const int nr = min(cnt, 64);

    float acc[8] = {0.f, 0.f, 0.f, 0.f, 0.f, 0.f, 0.f, 0.f};

    if constexpr (D == 128) {
        const int quad = lane >> 4;
        const int l16  = lane & 15;
        const int rem = nr & 15;
        if (rem) {
            // masked head: edges [0, rem) via slots {quad, 4+quad, 8+quad, 12+quad}
            float w0 = __shfl(wv, quad),      w1 = __shfl(wv, 4 + quad);
            float w2 = __shfl(wv, 8 + quad),  w3 = __shfl(wv, 12 + quad);
            int   s0 = __shfl(sv, quad),      s1 = __shfl(sv, 4 + quad);
            int   s2 = __shfl(sv, 8 + quad),  s3 = __shfl(sv, 12 + quad);
            w0 = (quad      < rem) ? w0 : 0.f;
            w1 = (4 + quad  < rem) ? w1 : 0.f;
            w2 = (8 + quad  < rem) ? w2 : 0.f;
            w3 = (12 + quad < rem) ? w3 : 0.f;
            half8 h0 = mrow[(size_t)s0 * 16 + l16];
            half8 h1 = mrow[(size_t)s1 * 16 + l16];
            half8 h2 = mrow[(size_t)s2 * 16 + l16];
            half8 h3 = mrow[(size_t)s3 * 16 + l16];
#pragma unroll
            for (int i = 0; i < 8; ++i) {
                acc[i] = fmaf(w0, (float)h0[i], acc[i]);
                acc[i] = fmaf(w1, (float)h1[i], acc[i]);
                acc[i] = fmaf(w2, (float)h2[i], acc[i]);
                acc[i] = fmaf(w3, (float)h3[i], acc[i]);
            }
        }
        for (int k = rem; k < nr; k += 16) {
            float w0 = __shfl(wv, k + quad),      w1 = __shfl(wv, k + 4 + quad);
            float w2 = __shfl(wv, k + 8 + quad),  w3 = __shfl(wv, k + 12 + quad);
            int   s0 = __shfl(sv, k + quad),      s1 = __shfl(sv, k + 4 + quad);
            int   s2 = __shfl(sv, k + 8 + quad),  s3 = __shfl(sv, k + 12 + quad);
            half8 h0 = mrow[(size_t)s0 * 16 + l16];
            half8 h1 = mrow[(size_t)s1 * 16 + l16];
            half8 h2 = mrow[(size_t)s2 * 16 + l16];
            half8 h3 = mrow[(size_t)s3 * 16 + l16];
#pragma unroll
            for (int i = 0; i < 8; ++i) {
                acc[i] = fmaf(w0, (float)h0[i], acc[i]);
                acc[i] = fmaf(w1, (float)h1[i], acc[i]);
                acc[i] = fmaf(w2, (float)h2[i], acc[i]);
                acc[i] = fmaf(w3, (float)h3[i], acc[i]);
            }
        }
        // rare: degree > 64 tail, per-quad strided
        for (int k = beg + 64 + quad; k < end; k += 4) {
            const int2 e0 = csr[k];
            const int  s0 = e0.y & 0xFFFF;
            const float w0 = __int_as_float(e0.x) * dinv[s0];
            half8 hv = mrow[(size_t)s0 * 16 + l16];
#pragma unroll
            for (int i = 0; i < 8; ++i)
                acc[i] = fmaf(w0, (float)hv[i], acc[i]);
        }
#pragma unroll
        for (int i = 0; i < 8; ++i) {
            acc[i] += __shfl_xor(acc[i], 16);
            acc[i] += __shfl_xor(acc[i], 32);
        }
        if (quad == 0) {
            const float dv = dinv[node];
            const float4 b0 = *(const float4*)(bias + l16 * 8);
            const float4 b1 = *(const float4*)(bias + l16 * 8 + 4);
            const float bb[8] = {b0.x, b0.y, b0.z, b0.w, b1.x, b1.y, b1.z, b1.w};
            half8 ho;
#pragma unroll
            for (int i = 0; i < 8; ++i)
                ho[i] = (_Float16)fmaxf(acc[i] * dv + bb[i], 0.f);
            *(half8*)((__half*)out + (size_t)node * 128 + l16 * 8) = ho;
        }
    } else {
        // D == 64
        const int oct = lane >> 3;
        const int l8  = lane & 7;
        const int rem = nr & 31;
        if (rem) {
            // masked head: edges [0, rem) via slots {oct, 8+oct, 16+oct, 24+oct}
            float w0 = __shfl(wv, oct),       w1 = __shfl(wv, 8 + oct);
            float w2 = __shfl(wv, 16 + oct),  w3 = __shfl(wv, 24 + oct);
            int   s0 = __shfl(sv, oct),       s1 = __shfl(sv, 8 + oct);
            int   s2 = __shfl(sv, 16 + oct),  s3 = __shfl(sv, 24 + oct);
            w0 = (oct      < rem) ? w0 : 0.f;
            w1 = (8 + oct  < rem) ? w1 : 0.f;
            w2 = (16 + oct < rem) ? w2 : 0.f;
            w3 = (24 + oct < rem) ? w3 : 0.f;
            half8 h0 = mrow[(size_t)s0 * 8 + l8];
            half8 h1 = mrow[(size_t)s1 * 8 + l8];
            half8 h2 = mrow[(size_t)s2 * 8 + l8];
            half8 h3 = mrow[(size_t)s3 * 8 + l8];
#pragma unroll
            for (int i = 0; i < 8; ++i) {
                acc[i] = fmaf(w0, (float)h0[i], acc[i]);
                acc[i] = fmaf(w1, (float)h1[i], acc[i]);
                acc[i] = fmaf(w2, (float)h2[i], acc[i]);
                acc[i] = fmaf(w3, (float)h3[i], acc[i]);
            }
        }
        for (int k = rem; k < nr; k += 32) {
            float w0 = __shfl(wv, k + oct),       w1 = __shfl(wv, k + 8 + oct);
            float w2 = __shfl(wv, k + 16 + oct),  w3 = __shfl(wv, k + 24 + oct);
            int   s0 = __shfl(sv, k + oct),       s1 = __shfl(sv, k + 8 + oct);
            int   s2 = __shfl(sv, k + 16 + oct),  s3 = __shfl(sv, k + 24 + oct);
            half8 h0 = mrow[(size_t)s0 * 8 + l8];
            half8 h1 = mrow[(size_t)s1 * 8 + l8];
            half8 h2 = mrow[(size_t)s2 * 8 + l8];
            half8 h3 = mrow[(size_t)s3 * 8 + l8];
#pragma unroll
            for (int i = 0; i < 8; ++i) {
                acc[i] = fmaf(w0, (float)h0[i], acc[i]);
                acc[i] = fmaf(w1, (float)h1[i], acc[i]);
                acc[i] = fmaf(w2, (float)h2[i], acc[i]);
                acc[i] = fmaf(w3, (float)h3[i], acc[i]);
            }
        }
        for (int k = beg + 64 + oct; k < end; k += 8) {
            const int2 e0 = csr[k];
            const int  s0 = e0.y & 0xFFFF;
            const float w0 = __int_as_float(e0.x) * dinv[s0];
            half8 hv = mrow[(size_t)s0 * 8 + l8];
#pragma unroll
            for (int i = 0; i < 8; ++i)
                acc[i] = fmaf(w0, (float)hv[i], acc[i]);
        }
#pragma unroll
        for (int i = 0; i < 8; ++i) {
            acc[i] += __shfl_xor(acc[i], 8);
            acc[i] += __shfl_xor(acc[i], 16);
            acc[i] += __shfl_xor(acc[i], 32);
        }
        if (oct == 0) {
            const float dv = dinv[node];
            const float4 b0 = *(const float4*)(bias + l8 * 8);
            const float4 b1 = *(const float4*)(bias + l8 * 8 + 4);
            float4 v0, v1;
            v0.x = fmaxf(acc[0] * dv + b0.x, 0.f);
            v0.y = fmaxf(acc[1] * dv + b0.y, 0.f);
            v0.z = fmaxf(acc[2] * dv + b0.z, 0.f);
            v0.w = fmaxf(acc[3] * dv + b0.w, 0.f);
            v1.x = fmaxf(acc[4] * dv + b1.x, 0.f);
            v1.y = fmaxf(acc[5] * dv + b1.y, 0.f);
            v1.z = fmaxf(acc[6] * dv + b1.z, 0.f);
            v1.w = fmaxf(acc[7] * dv + b1.w, 0.f);
            float* op = (float*)out + (size_t)node * 64 + l8 * 8;
            *(float4*)op = v0;
            *(float4*)(op + 4) = v1;
        }
    }
}

// ---------------- launch ----------------

extern "C" void kernel_launch(void* const* d_in, const int* in_sizes, int n_in,
                              void* d_out, int out_size, void* d_ws, size_t ws_size,
                              hipStream_t stream) {
    const float* x  = (const float*)d_in[0];
    const int*   ei = (const int*)d_in[1];   // [2, E] int32
    const float* ew = (const float*)d_in[2];
    const float* W1 = (const float*)d_in[3];
    const float* b1 = (const float*)d_in[4];
    const float* W2 = (const float*)d_in[5];
    const float* b2 = (const float*)d_in[6];
    const float* W3 = (const float*)d_in[7];
    const float* b3 = (const float*)d_in[8];
    float* out = (float*)d_out;

    const int N = in_sizes[0] / K_DIM;      // 50000
    const int E = in_sizes[2];              // 800000
    const int* row = ei;                    // edge_index[0] (source)
    const int* col = ei + E;                // edge_index[1] (target / aggregation)

    const int total = E + N;                         // 850000
    const int nb = (total + SORT_ITEMS - 1) / SORT_ITEMS;   // 208
    const int ngroups = (N + 255) >> 8;              // 196 high-byte groups
    const int NW1 = 128 * 128, NW2 = 128 * 128, NW3 = 64 * 128;
    const int nwb = (NW1 + NW2 + NW3 + 255) / 256;   // 160 weight-convert blocks

    // workspace layout, 8B-aligned sections first
    u64* elA      = (u64*)d_ws;                                // total
    u64* elB      = elA + total;                               // total
    __half* m_buf = (__half*)(elB + total);                    // N*128 fp16
    __half* h_buf = m_buf + (size_t)N * K_DIM;                 // N*128 fp16
    __half* Wh    = h_buf + (size_t)N * K_DIM;                 // 40960 fp16
    u32* ghist    = (u32*)(Wh + NW1 + NW2 + NW3);              // 256*nb
    u32* dsum     = ghist + (size_t)256 * nb;                  // 256
    u32* dbase    = dsum + 256;                                // 257
    int* offs     = (int*)(dbase + 257);                       // N+1
    float* dinv   = (float*)(offs + N + 1);                    // N

    build_hist<<<nb + nwb, 256, 0, stream>>>(row, col, ew, elA, ghist, E, N, nb,
                                             W1, W2, W3, Wh, NW1, NW2, NW3);
    digit_sum<<<256, 256, 0, stream>>>(ghist, dsum, nb);
    digit_scan<<<256, 256, 0, stream>>>(ghist, dsum, dbase, nb);

    // gemm1 front half rides in the p1 launch: rows [0, g1rows)
    const int g1blocks = 392;                        // 64-row tiles
    const int g1rows = g1blocks * 64;                // 25088
    p1_gemm<<<nb + g1blocks, 256, 0, stream>>>(elA, ghist, elB, total, nb,
                                               x, Wh, m_buf, N);

    // gemm1 back half rides in the p2 launch: rows [g1rows, N)
    const int g2blocks = (N - g1rows + 255) / 256;   // 98 16-wave tiles
    p2_gemm<<<ngroups + g2blocks, 1024, 0, stream>>>(
        elB, elA, dbase, offs, dinv, N, ngroups, x, Wh, m_buf, g1rows);

    const int gemm_blocks = (N + 63) / 64;
    const int agg_blocks = (N + 3) / 4;
    const int2* csr = (const int2*)elA;

    // layer 1 agg: h = fp16(relu(dinv_n * sum (ew*dinv_s)*m_raw + b1))
    agg_kernel<128, __half><<<agg_blocks, 256, 0, stream>>>(m_buf, offs, csr, dinv, b1, h_buf, N);
    // layer 2
    mfma_gemm<128><<<gemm_blocks, 256, 0, stream>>>(h_buf, Wh + NW1, m_buf, N);
    agg_kernel<128, __half><<<agg_blocks, 256, 0, stream>>>(m_buf, offs, csr, dinv, b2, h_buf, N);
    // layer 3: F_OUT=64, write d_out (fp32) directly
    mfma_gemm<64><<<gemm_blocks, 256, 0, stream>>>(h_buf, Wh + NW1 + NW2, m_buf, N);
    agg_kernel<64, float><<<agg_blocks, 256, 0, stream>>>(m_buf, offs, csr, dinv, b3, out, N);
}